// Round 1
// baseline (1423.025 us; speedup 1.0000x reference)
//
#include <hip/hip_runtime.h>

// ---------------------------------------------------------------------------
// PraxisBlock: rmsnorm -> QKV -> causal MHA -> O+residual -> rmsnorm ->
//              router top2/8 -> gathered expert FFN (gelu) -> combine
// All GEMMs: fp16 MFMA (v_mfma_f32_16x16x32_f16), fp32 accumulate.
// Router/topk/loss in fp32 for selection fidelity.
// ---------------------------------------------------------------------------

typedef _Float16 f16;
typedef _Float16 f16x8 __attribute__((ext_vector_type(8)));
typedef _Float16 f16x4v __attribute__((ext_vector_type(4)));
typedef float f32x4 __attribute__((ext_vector_type(4)));

#define DMODEL 1024
#define NHEAD  16
#define HDIM   64
#define NEXP   8
#define DFFN   4096
#define NBATCH 2
#define NSEQ   2048
#define NTOK   4096   // NBATCH*NSEQ
#define NPAIR  8192   // NTOK*2

// ---- workspace byte offsets (all 256-aligned) ----
#define OFF_WQKVT  0ull                  // 3*1024*1024 f16
#define OFF_WOT    6291456ull            // 1024*1024 f16
#define OFF_W1T    8388608ull            // 8*4096*1024 f16
#define OFF_W2T    75497472ull           // 8*1024*4096 f16
#define OFF_HATTN  142606336ull          // 4096*1024 f16
#define OFF_Q      150994944ull          // 32*2048*64 f16
#define OFF_K      159383552ull
#define OFF_VT     167772160ull
#define OFF_OC     176160768ull          // 4096*1024 f16
#define OFF_XMID   184549376ull          // 4096*1024 f32
#define OFF_HMLP   201326592ull          // 4096*1024 f16
#define OFF_HID    209715200ull          // 8192*4096 f16
#define OFF_Y      276824064ull          // 8192*1024 f32
#define OFF_LIST   310378496ull          // 8*4096 int
#define OFF_METAI  310509568ull          // 4096 int4
#define OFF_METAS  310575104ull          // 4096 float2
#define OFF_CNT    310607872ull          // 8 int   (memset 0)
#define OFF_PSUM   310607904ull          // 8 float (memset 0)
#define OFF_BASE   310607936ull          // 9 int

__device__ __forceinline__ void ldsAsync16(const void* g, void* l) {
  __builtin_amdgcn_global_load_lds((const __attribute__((address_space(1))) void*)g,
                                   (__attribute__((address_space(3))) void*)l, 16, 0, 0);
}

// ---------------- transpose + cast fp32[R][C] -> fp16[C][R] ----------------
__global__ void transpose_cast_kernel(const float* __restrict__ src, f16* __restrict__ dst,
                                      int R, int C) {
  __shared__ float tile[32][33];
  const size_t zoff = (size_t)blockIdx.z * R * C;
  src += zoff; dst += zoff;
  int c0 = blockIdx.x * 32, r0 = blockIdx.y * 32;
  int tx = threadIdx.x, ty = threadIdx.y;
#pragma unroll
  for (int i = 0; i < 4; i++)
    tile[ty + i * 8][tx] = src[(size_t)(r0 + ty + i * 8) * C + c0 + tx];
  __syncthreads();
#pragma unroll
  for (int i = 0; i < 4; i++)
    dst[(size_t)(c0 + ty + i * 8) * R + r0 + tx] = (f16)tile[tx][ty + i * 8];
}

// ---------------- rmsnorm fp32 -> fp16 ----------------
__global__ void rmsnorm_kernel(const float* __restrict__ x, const float* __restrict__ w,
                               f16* __restrict__ out) {
  int t = blockIdx.x, tid = threadIdx.x;
  float4 v = ((const float4*)(x + (size_t)t * DMODEL))[tid];
  float ss = v.x * v.x + v.y * v.y + v.z * v.z + v.w * v.w;
#pragma unroll
  for (int o = 32; o > 0; o >>= 1) ss += __shfl_down(ss, o);
  __shared__ float red[4];
  if ((tid & 63) == 0) red[tid >> 6] = ss;
  __syncthreads();
  float tot = red[0] + red[1] + red[2] + red[3];
  float rstd = rsqrtf(tot / (float)DMODEL + 1e-6f);
  float4 wv = ((const float4*)w)[tid];
  f16x4v o4;
  o4[0] = (f16)(v.x * rstd * wv.x);
  o4[1] = (f16)(v.y * rstd * wv.y);
  o4[2] = (f16)(v.z * rstd * wv.z);
  o4[3] = (f16)(v.w * rstd * wv.w);
  *(f16x4v*)(out + (size_t)t * DMODEL + tid * 4) = o4;
}

// ---------------- shared 128x128xK MFMA core ----------------
template <class EPI>
__device__ __forceinline__ void gemm128(const f16* aP0, const f16* aP1, const f16* aP2, const f16* aP3,
                                        const f16* bP0, const f16* bP1, const f16* bP2, const f16* bP3,
                                        int K, EPI epi) {
  __shared__ __align__(16) f16 sA[128 * 64];
  __shared__ __align__(16) f16 sB[128 * 64];
  const int tid = threadIdx.x;
  const int lane = tid & 63, wave = tid >> 6;
  const int wm = (wave >> 1) * 64, wn = (wave & 1) * 64;
  const int q4 = lane >> 4, l15 = lane & 15;
  const f16* aP[4] = {aP0, aP1, aP2, aP3};
  const f16* bP[4] = {bP0, bP1, bP2, bP3};
  f32x4 zero = {0.f, 0.f, 0.f, 0.f};
  f32x4 acc[4][4];
#pragma unroll
  for (int i = 0; i < 4; i++)
#pragma unroll
    for (int j = 0; j < 4; j++) acc[i][j] = zero;

  for (int k0 = 0; k0 < K; k0 += 64) {
    __syncthreads();
#pragma unroll
    for (int i = 0; i < 4; i++) {
      ldsAsync16(aP[i] + k0, &sA[(i * 4 + wave) * 512]);
      ldsAsync16(bP[i] + k0, &sB[(i * 4 + wave) * 512]);
    }
    __syncthreads();
#pragma unroll
    for (int kk = 0; kk < 2; kk++) {
      f16x8 af[4], bf[4];
#pragma unroll
      for (int mi = 0; mi < 4; mi++)
        af[mi] = *(const f16x8*)&sA[(wm + mi * 16 + l15) * 64 + kk * 32 + q4 * 8];
#pragma unroll
      for (int ni = 0; ni < 4; ni++)
        bf[ni] = *(const f16x8*)&sB[(wn + ni * 16 + l15) * 64 + kk * 32 + q4 * 8];
#pragma unroll
      for (int mi = 0; mi < 4; mi++)
#pragma unroll
        for (int ni = 0; ni < 4; ni++)
          acc[mi][ni] = __builtin_amdgcn_mfma_f32_16x16x32_f16(af[mi], bf[ni], acc[mi][ni], 0, 0, 0);
    }
  }
#pragma unroll
  for (int mi = 0; mi < 4; mi++)
#pragma unroll
    for (int ni = 0; ni < 4; ni++)
#pragma unroll
      for (int r = 0; r < 4; r++)
        epi(wm + mi * 16 + q4 * 4 + r, wn + ni * 16 + l15, acc[mi][ni][r]);
}

// ---------------- QKV projection (N=3072 stacked) ----------------
__global__ __launch_bounds__(256, 2) void gemm_qkv_kernel(
    const f16* __restrict__ hA, const f16* __restrict__ wT,
    f16* __restrict__ qb, f16* __restrict__ kb, f16* __restrict__ vtb) {
  int mt = blockIdx.y, nt = blockIdx.x;
  int tid = threadIdx.x, lane = tid & 63, wave = tid >> 6;
  int kc = lane & 7, rs = lane >> 3;
  const f16 *a[4], *b[4];
#pragma unroll
  for (int i = 0; i < 4; i++) {
    int row = i * 32 + wave * 8 + rs;
    a[i] = hA + (size_t)(mt * 128 + row) * DMODEL + kc * 8;
    b[i] = wT + (size_t)(nt * 128 + row) * DMODEL + kc * 8;
  }
  int mB = mt * 128, nB = nt * 128;
  gemm128(a[0], a[1], a[2], a[3], b[0], b[1], b[2], b[3], DMODEL,
    [&](int r, int c, float v) {
      int m = mB + r, n = nB + c;
      int mat = n >> 10, nn = n & 1023;
      int h = nn >> 6, d = nn & 63;
      int bI = m >> 11, s = m & 2047;
      int bh = bI * NHEAD + h;
      f16 hv = (f16)v;
      if (mat == 0)      qb[((size_t)bh * NSEQ + s) * HDIM + d] = hv;
      else if (mat == 1) kb[((size_t)bh * NSEQ + s) * HDIM + d] = hv;
      else               vtb[((size_t)bh * HDIM + d) * NSEQ + s] = hv;
    });
}

// ---------------- O projection + residual ----------------
__global__ __launch_bounds__(256, 2) void gemm_o_kernel(
    const f16* __restrict__ oc, const f16* __restrict__ woT,
    const float* __restrict__ xin, float* __restrict__ xmid) {
  int mt = blockIdx.y, nt = blockIdx.x;
  int tid = threadIdx.x, lane = tid & 63, wave = tid >> 6;
  int kc = lane & 7, rs = lane >> 3;
  const f16 *a[4], *b[4];
#pragma unroll
  for (int i = 0; i < 4; i++) {
    int row = i * 32 + wave * 8 + rs;
    a[i] = oc + (size_t)(mt * 128 + row) * DMODEL + kc * 8;
    b[i] = woT + (size_t)(nt * 128 + row) * DMODEL + kc * 8;
  }
  int mB = mt * 128, nB = nt * 128;
  gemm128(a[0], a[1], a[2], a[3], b[0], b[1], b[2], b[3], DMODEL,
    [&](int r, int c, float v) {
      size_t idx = (size_t)(mB + r) * DMODEL + nB + c;
      xmid[idx] = xin[idx] + v;
    });
}

// ---------------- MoE expert GEMM 1: h -> gelu(h*w1+b1) ----------------
__global__ __launch_bounds__(256, 2) void gemm_moe1_kernel(
    const f16* __restrict__ hM, const f16* __restrict__ w1T, const float* __restrict__ b1,
    const int* __restrict__ cnt, const int* __restrict__ base, const int* __restrict__ list,
    f16* __restrict__ hid) {
  int e = blockIdx.z, mt = blockIdx.y, nt = blockIdx.x;
  int c_e = cnt[e];
  if (mt * 128 >= c_e) return;
  int tid = threadIdx.x, lane = tid & 63, wave = tid >> 6;
  int kc = lane & 7, rs = lane >> 3;
  const f16 *a[4], *b[4];
#pragma unroll
  for (int i = 0; i < 4; i++) {
    int row = i * 32 + wave * 8 + rs;
    int rr = mt * 128 + row; rr = rr < c_e ? rr : c_e - 1;
    int tok = list[e * NTOK + rr];
    a[i] = hM + (size_t)tok * DMODEL + kc * 8;
    b[i] = w1T + ((size_t)e * DFFN + nt * 128 + row) * DMODEL + kc * 8;
  }
  int rowBase = base[e] + mt * 128, nB = nt * 128, mLoc = mt * 128;
  gemm128(a[0], a[1], a[2], a[3], b[0], b[1], b[2], b[3], DMODEL,
    [&](int r, int c, float v) {
      if (mLoc + r < c_e) {
        float v2 = v + b1[e * DFFN + nB + c];
        float u = 1.5957691216057308f * (v2 + 0.044715f * v2 * v2 * v2); // 2*0.79788456*
        float th = 1.f - 2.f / (__expf(u) + 1.f);                        // tanh
        hid[(size_t)(rowBase + r) * DFFN + nB + c] = (f16)(0.5f * v2 * (1.f + th));
      }
    });
}

// ---------------- MoE expert GEMM 2: hid*w2+b2 -> y ----------------
__global__ __launch_bounds__(256, 2) void gemm_moe2_kernel(
    const f16* __restrict__ hid, const f16* __restrict__ w2T, const float* __restrict__ b2,
    const int* __restrict__ cnt, const int* __restrict__ base, float* __restrict__ y) {
  int e = blockIdx.z, mt = blockIdx.y, nt = blockIdx.x;
  int c_e = cnt[e];
  if (mt * 128 >= c_e) return;
  int tid = threadIdx.x, lane = tid & 63, wave = tid >> 6;
  int kc = lane & 7, rs = lane >> 3;
  int bse = base[e];
  const f16 *a[4], *b[4];
#pragma unroll
  for (int i = 0; i < 4; i++) {
    int row = i * 32 + wave * 8 + rs;
    int rr = mt * 128 + row; rr = rr < c_e ? rr : c_e - 1;
    a[i] = hid + (size_t)(bse + rr) * DFFN + kc * 8;
    b[i] = w2T + ((size_t)e * DMODEL + nt * 128 + row) * DFFN + kc * 8;
  }
  int nB = nt * 128, mLoc = mt * 128;
  gemm128(a[0], a[1], a[2], a[3], b[0], b[1], b[2], b[3], DFFN,
    [&](int r, int c, float v) {
      if (mLoc + r < c_e)
        y[(size_t)(bse + mLoc + r) * DMODEL + nB + c] = v + b2[e * DMODEL + nB + c];
    });
}

// ---------------- flash attention (causal + key mask) ----------------
__global__ __launch_bounds__(256, 1) void attn_kernel(
    const f16* __restrict__ qb, const f16* __restrict__ kb, const f16* __restrict__ vtb,
    const int* __restrict__ amask, f16* __restrict__ oc) {
  int qt = blockIdx.x, bh = blockIdx.y;
  int bI = bh >> 4, h = bh & 15;
  int qbase = qt * 256;
  int tid = threadIdx.x, lane = tid & 63, wave = tid >> 6;
  int q4 = lane >> 4, l15 = lane & 15;
  int kc = lane & 7, rs = lane >> 3;

  __shared__ __align__(16) f16 sQ[4 * 64 * 64];
  __shared__ __align__(16) f16 sK[64 * 64];
  __shared__ __align__(16) f16 sVT[64 * 64];
  __shared__ __align__(16) f16 sP[4 * 64 * 64];
  __shared__ int sMask[64];

  const f16* qBH = qb + (size_t)bh * NSEQ * HDIM;
  const f16* kBH = kb + (size_t)bh * NSEQ * HDIM;
  const f16* vBH = vtb + (size_t)bh * HDIM * NSEQ;

#pragma unroll
  for (int i = 0; i < 8; i++) {
    int row = i * 32 + wave * 8 + rs;  // 0..255
    ldsAsync16(qBH + (size_t)(qbase + row) * HDIM + kc * 8, &sQ[(i * 4 + wave) * 512]);
  }

  f32x4 zero = {0.f, 0.f, 0.f, 0.f};
  f32x4 accO[4][4];
  float mrow[4][4], lrow[4][4];
#pragma unroll
  for (int i = 0; i < 4; i++)
#pragma unroll
    for (int j = 0; j < 4; j++) {
      accO[i][j] = zero; mrow[i][j] = -3.0e38f; lrow[i][j] = 0.f;
    }
  int qmax = qbase + wave * 64 + 63;
  int nkt = (qt + 1) * 4;
  f16* sPw = &sP[wave * 4096];
  const f16* sQw = &sQ[wave * 4096];

  for (int kt = 0; kt < nkt; kt++) {
    int kb0 = kt * 64;
    __syncthreads();
#pragma unroll
    for (int i = 0; i < 2; i++) {
      int row = i * 32 + wave * 8 + rs;  // 0..63
      ldsAsync16(kBH + (size_t)(kb0 + row) * HDIM + kc * 8, &sK[(i * 4 + wave) * 512]);
      ldsAsync16(vBH + (size_t)row * NSEQ + kb0 + kc * 8, &sVT[(i * 4 + wave) * 512]);
    }
    if (tid < 64) sMask[tid] = amask[bI * NSEQ + kb0 + tid];
    __syncthreads();

    if (kb0 <= qmax) {
      f32x4 accS[4][4];
#pragma unroll
      for (int i = 0; i < 4; i++)
#pragma unroll
        for (int j = 0; j < 4; j++) accS[i][j] = zero;
#pragma unroll
      for (int kk = 0; kk < 2; kk++) {
        f16x8 af[4], bf[4];
#pragma unroll
        for (int mi = 0; mi < 4; mi++)
          af[mi] = *(const f16x8*)&sQw[(mi * 16 + l15) * 64 + kk * 32 + q4 * 8];
#pragma unroll
        for (int nj = 0; nj < 4; nj++)
          bf[nj] = *(const f16x8*)&sK[(nj * 16 + l15) * 64 + kk * 32 + q4 * 8];
#pragma unroll
        for (int mi = 0; mi < 4; mi++)
#pragma unroll
          for (int nj = 0; nj < 4; nj++)
            accS[mi][nj] = __builtin_amdgcn_mfma_f32_16x16x32_f16(af[mi], bf[nj], accS[mi][nj], 0, 0, 0);
      }
      int gk[4]; bool mok[4];
#pragma unroll
      for (int nj = 0; nj < 4; nj++) {
        gk[nj] = kb0 + nj * 16 + l15;
        mok[nj] = sMask[nj * 16 + l15] > 0;
      }
#pragma unroll
      for (int mi = 0; mi < 4; mi++) {
#pragma unroll
        for (int r = 0; r < 4; r++) {
          int gq = qbase + wave * 64 + mi * 16 + q4 * 4 + r;
          float rm = -3.0e38f;
#pragma unroll
          for (int nj = 0; nj < 4; nj++) {
            float s = accS[mi][nj][r] * 0.125f;
            s = (mok[nj] && gk[nj] <= gq) ? s : -1.0e9f;
            accS[mi][nj][r] = s;
            rm = fmaxf(rm, s);
          }
#pragma unroll
          for (int o = 1; o < 16; o <<= 1) rm = fmaxf(rm, __shfl_xor(rm, o));
          float mold = mrow[mi][r];
          float mnew = fmaxf(mold, rm);
          float alpha = __expf(mold - mnew);
          float rsum = 0.f;
#pragma unroll
          for (int nj = 0; nj < 4; nj++) {
            float p = __expf(accS[mi][nj][r] - mnew);
            accS[mi][nj][r] = p;
            rsum += p;
          }
#pragma unroll
          for (int o = 1; o < 16; o <<= 1) rsum += __shfl_xor(rsum, o);
          lrow[mi][r] = lrow[mi][r] * alpha + rsum;
          mrow[mi][r] = mnew;
#pragma unroll
          for (int dj = 0; dj < 4; dj++) accO[mi][dj][r] *= alpha;
          int prow = mi * 16 + q4 * 4 + r;
#pragma unroll
          for (int nj = 0; nj < 4; nj++)
            sPw[prow * 64 + nj * 16 + l15] = (f16)accS[mi][nj][r];
        }
      }
      // PV
#pragma unroll
      for (int kk = 0; kk < 2; kk++) {
        f16x8 pf[4], vf[4];
#pragma unroll
        for (int mi = 0; mi < 4; mi++)
          pf[mi] = *(const f16x8*)&sPw[(mi * 16 + l15) * 64 + kk * 32 + q4 * 8];
#pragma unroll
        for (int dj = 0; dj < 4; dj++)
          vf[dj] = *(const f16x8*)&sVT[(dj * 16 + l15) * 64 + kk * 32 + q4 * 8];
#pragma unroll
        for (int mi = 0; mi < 4; mi++)
#pragma unroll
          for (int dj = 0; dj < 4; dj++)
            accO[mi][dj] = __builtin_amdgcn_mfma_f32_16x16x32_f16(pf[mi], vf[dj], accO[mi][dj], 0, 0, 0);
      }
    }
  }
  // epilogue: divide by l, scatter to o_concat[token][h*64+d]
#pragma unroll
  for (int mi = 0; mi < 4; mi++)
#pragma unroll
    for (int r = 0; r < 4; r++) {
      float inv = 1.f / lrow[mi][r];
      int s = qbase + wave * 64 + mi * 16 + q4 * 4 + r;
      size_t rowoff = ((size_t)bI * NSEQ + s) * DMODEL + h * HDIM;
#pragma unroll
      for (int dj = 0; dj < 4; dj++)
        oc[rowoff + dj * 16 + l15] = (f16)(accO[mi][dj][r] * inv);
    }
}

// ---------------- router: fp32 rmsnorm + logits + softmax + top2 ----------------
__global__ void router_kernel(const float* __restrict__ xmid, const float* __restrict__ normw,
                              const float* __restrict__ rw, int* __restrict__ cnt,
                              float* __restrict__ psum, int* __restrict__ list,
                              int4* __restrict__ metaI, float2* __restrict__ metaS) {
  int t = blockIdx.x, tid = threadIdx.x;
  float4 v = ((const float4*)(xmid + (size_t)t * DMODEL))[tid];
  float ss = v.x * v.x + v.y * v.y + v.z * v.z + v.w * v.w;
#pragma unroll
  for (int o = 32; o > 0; o >>= 1) ss += __shfl_down(ss, o);
  __shared__ float red[4];
  __shared__ float wred[4][8];
  if ((tid & 63) == 0) red[tid >> 6] = ss;
  __syncthreads();
  float rstd = rsqrtf((red[0] + red[1] + red[2] + red[3]) / (float)DMODEL + 1e-6f);
  float4 wv = ((const float4*)normw)[tid];
  float hd[4] = {v.x * rstd * wv.x, v.y * rstd * wv.y, v.z * rstd * wv.z, v.w * rstd * wv.w};
  float part[8] = {0, 0, 0, 0, 0, 0, 0, 0};
#pragma unroll
  for (int j = 0; j < 4; j++) {
    const float4* rr = (const float4*)(rw + (size_t)(tid * 4 + j) * NEXP);
    float4 a = rr[0], b = rr[1];
    part[0] += hd[j] * a.x; part[1] += hd[j] * a.y; part[2] += hd[j] * a.z; part[3] += hd[j] * a.w;
    part[4] += hd[j] * b.x; part[5] += hd[j] * b.y; part[6] += hd[j] * b.z; part[7] += hd[j] * b.w;
  }
#pragma unroll
  for (int o = 1; o < 64; o <<= 1)
#pragma unroll
    for (int e = 0; e < 8; e++) part[e] += __shfl_xor(part[e], o);
  if ((tid & 63) == 0)
#pragma unroll
    for (int e = 0; e < 8; e++) wred[tid >> 6][e] = part[e];
  __syncthreads();
  if (tid == 0) {
    float lg[8], probs[8];
    float mx = -3.0e38f;
#pragma unroll
    for (int e = 0; e < 8; e++) {
      lg[e] = wred[0][e] + wred[1][e] + wred[2][e] + wred[3][e];
      mx = fmaxf(mx, lg[e]);
    }
    float sum = 0.f;
#pragma unroll
    for (int e = 0; e < 8; e++) { probs[e] = __expf(lg[e] - mx); sum += probs[e]; }
    float inv = 1.f / sum;
#pragma unroll
    for (int e = 0; e < 8; e++) { probs[e] *= inv; atomicAdd(&psum[e], probs[e]); }
    int e0 = 0;
#pragma unroll
    for (int e = 1; e < 8; e++) if (lg[e] > lg[e0]) e0 = e;
    int e1 = (e0 == 0) ? 1 : 0;
#pragma unroll
    for (int e = 0; e < 8; e++) if (e != e0 && lg[e] > lg[e1]) e1 = e;
    int p0 = atomicAdd(&cnt[e0], 1);
    int p1 = atomicAdd(&cnt[e1], 1);
    list[e0 * NTOK + p0] = t;
    list[e1 * NTOK + p1] = t;
    metaI[t] = make_int4(e0, p0, e1, p1);
    metaS[t] = make_float2(probs[e0], probs[e1]);
  }
}

__global__ void finalize_kernel(const int* __restrict__ cnt, const float* __restrict__ psum,
                                int* __restrict__ base, float* __restrict__ out_tail) {
  if (threadIdx.x == 0) {
    int b = 0;
#pragma unroll
    for (int e = 0; e < 8; e++) { base[e] = b; b += cnt[e]; }
    base[8] = b;
    float loss = 0.f;
#pragma unroll
    for (int e = 0; e < 8; e++)
      loss += ((float)cnt[e] / (float)NPAIR) * (psum[e] / (float)NTOK);
    out_tail[0] = loss * (float)NEXP;
#pragma unroll
    for (int e = 0; e < 8; e++) out_tail[1 + e] = (float)cnt[e];
  }
}

// ---------------- final combine ----------------
__global__ void combine_kernel(const float* __restrict__ xmid, const float* __restrict__ yv,
                               const int4* __restrict__ metaI, const float2* __restrict__ metaS,
                               const int* __restrict__ base, float* __restrict__ out) {
  int t = blockIdx.x, tid = threadIdx.x;
  int4 mi = metaI[t];
  float2 sc = metaS[t];
  size_t s0 = (size_t)(base[mi.x] + mi.y) * DMODEL;
  size_t s1 = (size_t)(base[mi.z] + mi.w) * DMODEL;
  float4 a = ((const float4*)(xmid + (size_t)t * DMODEL))[tid];
  float4 y0 = ((const float4*)(yv + s0))[tid];
  float4 y1 = ((const float4*)(yv + s1))[tid];
  float4 o;
  o.x = a.x + sc.x * y0.x + sc.y * y1.x;
  o.y = a.y + sc.x * y0.y + sc.y * y1.y;
  o.z = a.z + sc.x * y0.z + sc.y * y1.z;
  o.w = a.w + sc.x * y0.w + sc.y * y1.w;
  ((float4*)(out + (size_t)t * DMODEL))[tid] = o;
}

// ---------------------------------------------------------------------------
extern "C" void kernel_launch(void* const* d_in, const int* in_sizes, int n_in,
                              void* d_out, int out_size, void* d_ws, size_t ws_size,
                              hipStream_t stream) {
  (void)in_sizes; (void)n_in; (void)out_size; (void)ws_size;
  const float* x    = (const float*)d_in[0];
  const int*   am   = (const int*)d_in[1];
  const float* anw  = (const float*)d_in[2];
  const float* wq   = (const float*)d_in[3];
  const float* wk   = (const float*)d_in[4];
  const float* wv   = (const float*)d_in[5];
  const float* wo   = (const float*)d_in[6];
  const float* mnw  = (const float*)d_in[7];
  const float* rw   = (const float*)d_in[8];
  const float* w1   = (const float*)d_in[9];
  const float* b1   = (const float*)d_in[10];
  const float* w2   = (const float*)d_in[11];
  const float* b2   = (const float*)d_in[12];
  float* out = (float*)d_out;
  char* ws = (char*)d_ws;

  f16* wqkvT = (f16*)(ws + OFF_WQKVT);
  f16* woT   = (f16*)(ws + OFF_WOT);
  f16* w1T   = (f16*)(ws + OFF_W1T);
  f16* w2T   = (f16*)(ws + OFF_W2T);
  f16* hattn = (f16*)(ws + OFF_HATTN);
  f16* qb    = (f16*)(ws + OFF_Q);
  f16* kb    = (f16*)(ws + OFF_K);
  f16* vtb   = (f16*)(ws + OFF_VT);
  f16* oc    = (f16*)(ws + OFF_OC);
  float* xmid = (float*)(ws + OFF_XMID);
  f16* hmlp  = (f16*)(ws + OFF_HMLP);
  f16* hid   = (f16*)(ws + OFF_HID);
  float* y   = (float*)(ws + OFF_Y);
  int* list  = (int*)(ws + OFF_LIST);
  int4* metaI = (int4*)(ws + OFF_METAI);
  float2* metaS = (float2*)(ws + OFF_METAS);
  int* cnt   = (int*)(ws + OFF_CNT);
  float* psum = (float*)(ws + OFF_PSUM);
  int* base  = (int*)(ws + OFF_BASE);

  (void)hipMemsetAsync(ws + OFF_CNT, 0, 64, stream);

  dim3 tb(32, 8, 1);
  transpose_cast_kernel<<<dim3(32, 32, 1), tb, 0, stream>>>(wq, wqkvT, 1024, 1024);
  transpose_cast_kernel<<<dim3(32, 32, 1), tb, 0, stream>>>(wk, wqkvT + 1024 * 1024, 1024, 1024);
  transpose_cast_kernel<<<dim3(32, 32, 1), tb, 0, stream>>>(wv, wqkvT + 2 * 1024 * 1024, 1024, 1024);
  transpose_cast_kernel<<<dim3(32, 32, 1), tb, 0, stream>>>(wo, woT, 1024, 1024);
  transpose_cast_kernel<<<dim3(128, 32, 8), tb, 0, stream>>>(w1, w1T, 1024, 4096);
  transpose_cast_kernel<<<dim3(32, 128, 8), tb, 0, stream>>>(w2, w2T, 4096, 1024);

  rmsnorm_kernel<<<NTOK, 256, 0, stream>>>(x, anw, hattn);
  gemm_qkv_kernel<<<dim3(24, 32), 256, 0, stream>>>(hattn, wqkvT, qb, kb, vtb);
  attn_kernel<<<dim3(8, 32), 256, 0, stream>>>(qb, kb, vtb, am, oc);
  gemm_o_kernel<<<dim3(8, 32), 256, 0, stream>>>(oc, woT, x, xmid);
  rmsnorm_kernel<<<NTOK, 256, 0, stream>>>(xmid, mnw, hmlp);
  router_kernel<<<NTOK, 256, 0, stream>>>(xmid, mnw, rw, cnt, psum, list, metaI, metaS);
  finalize_kernel<<<1, 64, 0, stream>>>(cnt, psum, base, out + (size_t)NTOK * DMODEL);
  gemm_moe1_kernel<<<dim3(32, 32, 8), 256, 0, stream>>>(hmlp, w1T, b1, cnt, base, list, hid);
  gemm_moe2_kernel<<<dim3(8, 32, 8), 256, 0, stream>>>(hid, w2T, b2, cnt, base, y);
  combine_kernel<<<NTOK, 256, 0, stream>>>(xmid, y, metaI, metaS, base, out);
}

// Round 2
// 942.622 us; speedup vs baseline: 1.5096x; 1.5096x over previous
//
#include <hip/hip_runtime.h>

// ---------------------------------------------------------------------------
// PraxisBlock: rmsnorm -> QKV -> causal MHA -> O+residual -> rmsnorm ->
//              router top2/8 -> gathered expert FFN (gelu) -> combine
// All GEMMs: fp16 MFMA (v_mfma_f32_16x16x32_f16), fp32 accumulate.
// R1: router restructured — NO per-token global atomics (was 515us of atomic
//     ping-pong across XCDs). Deterministic prefix-sum scatter instead.
// ---------------------------------------------------------------------------

typedef _Float16 f16;
typedef _Float16 f16x8 __attribute__((ext_vector_type(8)));
typedef _Float16 f16x4v __attribute__((ext_vector_type(4)));
typedef float f32x4 __attribute__((ext_vector_type(4)));

#define DMODEL 1024
#define NHEAD  16
#define HDIM   64
#define NEXP   8
#define DFFN   4096
#define NBATCH 2
#define NSEQ   2048
#define NTOK   4096   // NBATCH*NSEQ
#define NPAIR  8192   // NTOK*2

// ---- workspace byte offsets (all 256-aligned) ----
#define OFF_WQKVT  0ull                  // 3*1024*1024 f16
#define OFF_WOT    6291456ull            // 1024*1024 f16
#define OFF_W1T    8388608ull            // 8*4096*1024 f16
#define OFF_W2T    75497472ull           // 8*1024*4096 f16
#define OFF_HATTN  142606336ull          // 4096*1024 f16
#define OFF_Q      150994944ull          // 32*2048*64 f16
#define OFF_K      159383552ull
#define OFF_VT     167772160ull
#define OFF_OC     176160768ull          // 4096*1024 f16
#define OFF_XMID   184549376ull          // 4096*1024 f32
#define OFF_HMLP   201326592ull          // 4096*1024 f16
#define OFF_HID    209715200ull          // 8192*4096 f16
#define OFF_Y      276824064ull          // 8192*1024 f32
#define OFF_LIST   310378496ull          // 8*4096 int
#define OFF_METAE  310509568ull          // 4096 int2
#define OFF_METAP  310542336ull          // 4096 int2
#define OFF_METAS  310575104ull          // 4096 float2
#define OFF_BPSUM  310607872ull          // 1024*8 float (per-block prob sums)
#define OFF_CNT    310640640ull          // 8 int
#define OFF_PSUM   310640704ull          // 8 float
#define OFF_BASE   310640768ull          // 9 int

__device__ __forceinline__ void ldsAsync16(const void* g, void* l) {
  __builtin_amdgcn_global_load_lds((const __attribute__((address_space(1))) void*)g,
                                   (__attribute__((address_space(3))) void*)l, 16, 0, 0);
}

// ---------------- transpose + cast fp32[R][C] -> fp16[C][R] ----------------
__global__ void transpose_cast_kernel(const float* __restrict__ src, f16* __restrict__ dst,
                                      int R, int C) {
  __shared__ float tile[32][33];
  const size_t zoff = (size_t)blockIdx.z * R * C;
  src += zoff; dst += zoff;
  int c0 = blockIdx.x * 32, r0 = blockIdx.y * 32;
  int tx = threadIdx.x, ty = threadIdx.y;
#pragma unroll
  for (int i = 0; i < 4; i++)
    tile[ty + i * 8][tx] = src[(size_t)(r0 + ty + i * 8) * C + c0 + tx];
  __syncthreads();
#pragma unroll
  for (int i = 0; i < 4; i++)
    dst[(size_t)(c0 + ty + i * 8) * R + r0 + tx] = (f16)tile[tx][ty + i * 8];
}

// ---------------- rmsnorm fp32 -> fp16 ----------------
__global__ void rmsnorm_kernel(const float* __restrict__ x, const float* __restrict__ w,
                               f16* __restrict__ out) {
  int t = blockIdx.x, tid = threadIdx.x;
  float4 v = ((const float4*)(x + (size_t)t * DMODEL))[tid];
  float ss = v.x * v.x + v.y * v.y + v.z * v.z + v.w * v.w;
#pragma unroll
  for (int o = 32; o > 0; o >>= 1) ss += __shfl_down(ss, o);
  __shared__ float red[4];
  if ((tid & 63) == 0) red[tid >> 6] = ss;
  __syncthreads();
  float tot = red[0] + red[1] + red[2] + red[3];
  float rstd = rsqrtf(tot / (float)DMODEL + 1e-6f);
  float4 wv = ((const float4*)w)[tid];
  f16x4v o4;
  o4[0] = (f16)(v.x * rstd * wv.x);
  o4[1] = (f16)(v.y * rstd * wv.y);
  o4[2] = (f16)(v.z * rstd * wv.z);
  o4[3] = (f16)(v.w * rstd * wv.w);
  *(f16x4v*)(out + (size_t)t * DMODEL + tid * 4) = o4;
}

// ---------------- shared 128x128xK MFMA core ----------------
template <class EPI>
__device__ __forceinline__ void gemm128(const f16* aP0, const f16* aP1, const f16* aP2, const f16* aP3,
                                        const f16* bP0, const f16* bP1, const f16* bP2, const f16* bP3,
                                        int K, EPI epi) {
  __shared__ __align__(16) f16 sA[128 * 64];
  __shared__ __align__(16) f16 sB[128 * 64];
  const int tid = threadIdx.x;
  const int lane = tid & 63, wave = tid >> 6;
  const int wm = (wave >> 1) * 64, wn = (wave & 1) * 64;
  const int q4 = lane >> 4, l15 = lane & 15;
  const f16* aP[4] = {aP0, aP1, aP2, aP3};
  const f16* bP[4] = {bP0, bP1, bP2, bP3};
  f32x4 zero = {0.f, 0.f, 0.f, 0.f};
  f32x4 acc[4][4];
#pragma unroll
  for (int i = 0; i < 4; i++)
#pragma unroll
    for (int j = 0; j < 4; j++) acc[i][j] = zero;

  for (int k0 = 0; k0 < K; k0 += 64) {
    __syncthreads();
#pragma unroll
    for (int i = 0; i < 4; i++) {
      ldsAsync16(aP[i] + k0, &sA[(i * 4 + wave) * 512]);
      ldsAsync16(bP[i] + k0, &sB[(i * 4 + wave) * 512]);
    }
    __syncthreads();
#pragma unroll
    for (int kk = 0; kk < 2; kk++) {
      f16x8 af[4], bf[4];
#pragma unroll
      for (int mi = 0; mi < 4; mi++)
        af[mi] = *(const f16x8*)&sA[(wm + mi * 16 + l15) * 64 + kk * 32 + q4 * 8];
#pragma unroll
      for (int ni = 0; ni < 4; ni++)
        bf[ni] = *(const f16x8*)&sB[(wn + ni * 16 + l15) * 64 + kk * 32 + q4 * 8];
#pragma unroll
      for (int mi = 0; mi < 4; mi++)
#pragma unroll
        for (int ni = 0; ni < 4; ni++)
          acc[mi][ni] = __builtin_amdgcn_mfma_f32_16x16x32_f16(af[mi], bf[ni], acc[mi][ni], 0, 0, 0);
    }
  }
#pragma unroll
  for (int mi = 0; mi < 4; mi++)
#pragma unroll
    for (int ni = 0; ni < 4; ni++)
#pragma unroll
      for (int r = 0; r < 4; r++)
        epi(wm + mi * 16 + q4 * 4 + r, wn + ni * 16 + l15, acc[mi][ni][r]);
}

// ---------------- QKV projection (N=3072 stacked) ----------------
__global__ __launch_bounds__(256, 2) void gemm_qkv_kernel(
    const f16* __restrict__ hA, const f16* __restrict__ wT,
    f16* __restrict__ qb, f16* __restrict__ kb, f16* __restrict__ vtb) {
  int mt = blockIdx.y, nt = blockIdx.x;
  int tid = threadIdx.x, lane = tid & 63, wave = tid >> 6;
  int kc = lane & 7, rs = lane >> 3;
  const f16 *a[4], *b[4];
#pragma unroll
  for (int i = 0; i < 4; i++) {
    int row = i * 32 + wave * 8 + rs;
    a[i] = hA + (size_t)(mt * 128 + row) * DMODEL + kc * 8;
    b[i] = wT + (size_t)(nt * 128 + row) * DMODEL + kc * 8;
  }
  int mB = mt * 128, nB = nt * 128;
  gemm128(a[0], a[1], a[2], a[3], b[0], b[1], b[2], b[3], DMODEL,
    [&](int r, int c, float v) {
      int m = mB + r, n = nB + c;
      int mat = n >> 10, nn = n & 1023;
      int h = nn >> 6, d = nn & 63;
      int bI = m >> 11, s = m & 2047;
      int bh = bI * NHEAD + h;
      f16 hv = (f16)v;
      if (mat == 0)      qb[((size_t)bh * NSEQ + s) * HDIM + d] = hv;
      else if (mat == 1) kb[((size_t)bh * NSEQ + s) * HDIM + d] = hv;
      else               vtb[((size_t)bh * HDIM + d) * NSEQ + s] = hv;
    });
}

// ---------------- O projection + residual ----------------
__global__ __launch_bounds__(256, 2) void gemm_o_kernel(
    const f16* __restrict__ oc, const f16* __restrict__ woT,
    const float* __restrict__ xin, float* __restrict__ xmid) {
  int mt = blockIdx.y, nt = blockIdx.x;
  int tid = threadIdx.x, lane = tid & 63, wave = tid >> 6;
  int kc = lane & 7, rs = lane >> 3;
  const f16 *a[4], *b[4];
#pragma unroll
  for (int i = 0; i < 4; i++) {
    int row = i * 32 + wave * 8 + rs;
    a[i] = oc + (size_t)(mt * 128 + row) * DMODEL + kc * 8;
    b[i] = woT + (size_t)(nt * 128 + row) * DMODEL + kc * 8;
  }
  int mB = mt * 128, nB = nt * 128;
  gemm128(a[0], a[1], a[2], a[3], b[0], b[1], b[2], b[3], DMODEL,
    [&](int r, int c, float v) {
      size_t idx = (size_t)(mB + r) * DMODEL + nB + c;
      xmid[idx] = xin[idx] + v;
    });
}

// ---------------- MoE expert GEMM 1: h -> gelu(h*w1+b1) ----------------
__global__ __launch_bounds__(256, 2) void gemm_moe1_kernel(
    const f16* __restrict__ hM, const f16* __restrict__ w1T, const float* __restrict__ b1,
    const int* __restrict__ cnt, const int* __restrict__ base, const int* __restrict__ list,
    f16* __restrict__ hid) {
  int e = blockIdx.z, mt = blockIdx.y, nt = blockIdx.x;
  int c_e = cnt[e];
  if (mt * 128 >= c_e) return;
  int tid = threadIdx.x, lane = tid & 63, wave = tid >> 6;
  int kc = lane & 7, rs = lane >> 3;
  const f16 *a[4], *b[4];
#pragma unroll
  for (int i = 0; i < 4; i++) {
    int row = i * 32 + wave * 8 + rs;
    int rr = mt * 128 + row; rr = rr < c_e ? rr : c_e - 1;
    int tok = list[e * NTOK + rr];
    a[i] = hM + (size_t)tok * DMODEL + kc * 8;
    b[i] = w1T + ((size_t)e * DFFN + nt * 128 + row) * DMODEL + kc * 8;
  }
  int rowBase = base[e] + mt * 128, nB = nt * 128, mLoc = mt * 128;
  gemm128(a[0], a[1], a[2], a[3], b[0], b[1], b[2], b[3], DMODEL,
    [&](int r, int c, float v) {
      if (mLoc + r < c_e) {
        float v2 = v + b1[e * DFFN + nB + c];
        float u = 1.5957691216057308f * (v2 + 0.044715f * v2 * v2 * v2); // 2*0.79788456*
        float th = 1.f - 2.f / (__expf(u) + 1.f);                        // tanh
        hid[(size_t)(rowBase + r) * DFFN + nB + c] = (f16)(0.5f * v2 * (1.f + th));
      }
    });
}

// ---------------- MoE expert GEMM 2: hid*w2+b2 -> y ----------------
__global__ __launch_bounds__(256, 2) void gemm_moe2_kernel(
    const f16* __restrict__ hid, const f16* __restrict__ w2T, const float* __restrict__ b2,
    const int* __restrict__ cnt, const int* __restrict__ base, float* __restrict__ y) {
  int e = blockIdx.z, mt = blockIdx.y, nt = blockIdx.x;
  int c_e = cnt[e];
  if (mt * 128 >= c_e) return;
  int tid = threadIdx.x, lane = tid & 63, wave = tid >> 6;
  int kc = lane & 7, rs = lane >> 3;
  int bse = base[e];
  const f16 *a[4], *b[4];
#pragma unroll
  for (int i = 0; i < 4; i++) {
    int row = i * 32 + wave * 8 + rs;
    int rr = mt * 128 + row; rr = rr < c_e ? rr : c_e - 1;
    a[i] = hid + (size_t)(bse + rr) * DFFN + kc * 8;
    b[i] = w2T + ((size_t)e * DMODEL + nt * 128 + row) * DFFN + kc * 8;
  }
  int nB = nt * 128, mLoc = mt * 128;
  gemm128(a[0], a[1], a[2], a[3], b[0], b[1], b[2], b[3], DFFN,
    [&](int r, int c, float v) {
      if (mLoc + r < c_e)
        y[(size_t)(bse + mLoc + r) * DMODEL + nB + c] = v + b2[e * DMODEL + nB + c];
    });
}

// ---------------- flash attention (causal + key mask) ----------------
__global__ __launch_bounds__(256, 1) void attn_kernel(
    const f16* __restrict__ qb, const f16* __restrict__ kb, const f16* __restrict__ vtb,
    const int* __restrict__ amask, f16* __restrict__ oc) {
  int qt = blockIdx.x, bh = blockIdx.y;
  int bI = bh >> 4, h = bh & 15;
  int qbase = qt * 256;
  int tid = threadIdx.x, lane = tid & 63, wave = tid >> 6;
  int q4 = lane >> 4, l15 = lane & 15;
  int kc = lane & 7, rs = lane >> 3;

  __shared__ __align__(16) f16 sQ[4 * 64 * 64];
  __shared__ __align__(16) f16 sK[64 * 64];
  __shared__ __align__(16) f16 sVT[64 * 64];
  __shared__ __align__(16) f16 sP[4 * 64 * 64];
  __shared__ int sMask[64];

  const f16* qBH = qb + (size_t)bh * NSEQ * HDIM;
  const f16* kBH = kb + (size_t)bh * NSEQ * HDIM;
  const f16* vBH = vtb + (size_t)bh * HDIM * NSEQ;

#pragma unroll
  for (int i = 0; i < 8; i++) {
    int row = i * 32 + wave * 8 + rs;  // 0..255
    ldsAsync16(qBH + (size_t)(qbase + row) * HDIM + kc * 8, &sQ[(i * 4 + wave) * 512]);
  }

  f32x4 zero = {0.f, 0.f, 0.f, 0.f};
  f32x4 accO[4][4];
  float mrow[4][4], lrow[4][4];
#pragma unroll
  for (int i = 0; i < 4; i++)
#pragma unroll
    for (int j = 0; j < 4; j++) {
      accO[i][j] = zero; mrow[i][j] = -3.0e38f; lrow[i][j] = 0.f;
    }
  int qmax = qbase + wave * 64 + 63;
  int nkt = (qt + 1) * 4;
  f16* sPw = &sP[wave * 4096];
  const f16* sQw = &sQ[wave * 4096];

  for (int kt = 0; kt < nkt; kt++) {
    int kb0 = kt * 64;
    __syncthreads();
#pragma unroll
    for (int i = 0; i < 2; i++) {
      int row = i * 32 + wave * 8 + rs;  // 0..63
      ldsAsync16(kBH + (size_t)(kb0 + row) * HDIM + kc * 8, &sK[(i * 4 + wave) * 512]);
      ldsAsync16(vBH + (size_t)row * NSEQ + kb0 + kc * 8, &sVT[(i * 4 + wave) * 512]);
    }
    if (tid < 64) sMask[tid] = amask[bI * NSEQ + kb0 + tid];
    __syncthreads();

    if (kb0 <= qmax) {
      f32x4 accS[4][4];
#pragma unroll
      for (int i = 0; i < 4; i++)
#pragma unroll
        for (int j = 0; j < 4; j++) accS[i][j] = zero;
#pragma unroll
      for (int kk = 0; kk < 2; kk++) {
        f16x8 af[4], bf[4];
#pragma unroll
        for (int mi = 0; mi < 4; mi++)
          af[mi] = *(const f16x8*)&sQw[(mi * 16 + l15) * 64 + kk * 32 + q4 * 8];
#pragma unroll
        for (int nj = 0; nj < 4; nj++)
          bf[nj] = *(const f16x8*)&sK[(nj * 16 + l15) * 64 + kk * 32 + q4 * 8];
#pragma unroll
        for (int mi = 0; mi < 4; mi++)
#pragma unroll
          for (int nj = 0; nj < 4; nj++)
            accS[mi][nj] = __builtin_amdgcn_mfma_f32_16x16x32_f16(af[mi], bf[nj], accS[mi][nj], 0, 0, 0);
      }
      int gk[4]; bool mok[4];
#pragma unroll
      for (int nj = 0; nj < 4; nj++) {
        gk[nj] = kb0 + nj * 16 + l15;
        mok[nj] = sMask[nj * 16 + l15] > 0;
      }
#pragma unroll
      for (int mi = 0; mi < 4; mi++) {
#pragma unroll
        for (int r = 0; r < 4; r++) {
          int gq = qbase + wave * 64 + mi * 16 + q4 * 4 + r;
          float rm = -3.0e38f;
#pragma unroll
          for (int nj = 0; nj < 4; nj++) {
            float s = accS[mi][nj][r] * 0.125f;
            s = (mok[nj] && gk[nj] <= gq) ? s : -1.0e9f;
            accS[mi][nj][r] = s;
            rm = fmaxf(rm, s);
          }
#pragma unroll
          for (int o = 1; o < 16; o <<= 1) rm = fmaxf(rm, __shfl_xor(rm, o));
          float mold = mrow[mi][r];
          float mnew = fmaxf(mold, rm);
          float alpha = __expf(mold - mnew);
          float rsum = 0.f;
#pragma unroll
          for (int nj = 0; nj < 4; nj++) {
            float p = __expf(accS[mi][nj][r] - mnew);
            accS[mi][nj][r] = p;
            rsum += p;
          }
#pragma unroll
          for (int o = 1; o < 16; o <<= 1) rsum += __shfl_xor(rsum, o);
          lrow[mi][r] = lrow[mi][r] * alpha + rsum;
          mrow[mi][r] = mnew;
#pragma unroll
          for (int dj = 0; dj < 4; dj++) accO[mi][dj][r] *= alpha;
          int prow = mi * 16 + q4 * 4 + r;
#pragma unroll
          for (int nj = 0; nj < 4; nj++)
            sPw[prow * 64 + nj * 16 + l15] = (f16)accS[mi][nj][r];
        }
      }
      // PV
#pragma unroll
      for (int kk = 0; kk < 2; kk++) {
        f16x8 pf[4], vf[4];
#pragma unroll
        for (int mi = 0; mi < 4; mi++)
          pf[mi] = *(const f16x8*)&sPw[(mi * 16 + l15) * 64 + kk * 32 + q4 * 8];
#pragma unroll
        for (int dj = 0; dj < 4; dj++)
          vf[dj] = *(const f16x8*)&sVT[(dj * 16 + l15) * 64 + kk * 32 + q4 * 8];
#pragma unroll
        for (int mi = 0; mi < 4; mi++)
#pragma unroll
          for (int dj = 0; dj < 4; dj++)
            accO[mi][dj] = __builtin_amdgcn_mfma_f32_16x16x32_f16(pf[mi], vf[dj], accO[mi][dj], 0, 0, 0);
      }
    }
  }
  // epilogue: divide by l, scatter to o_concat[token][h*64+d]
#pragma unroll
  for (int mi = 0; mi < 4; mi++)
#pragma unroll
    for (int r = 0; r < 4; r++) {
      float inv = 1.f / lrow[mi][r];
      int s = qbase + wave * 64 + mi * 16 + q4 * 4 + r;
      size_t rowoff = ((size_t)bI * NSEQ + s) * DMODEL + h * HDIM;
#pragma unroll
      for (int dj = 0; dj < 4; dj++)
        oc[rowoff + dj * 16 + l15] = (f16)(accO[mi][dj][r] * inv);
    }
}

// ---------------- router: wave-per-token, NO global atomics ----------------
__global__ __launch_bounds__(256) void router_kernel(
    const float* __restrict__ xmid, const float* __restrict__ normw,
    const float* __restrict__ rw, int2* __restrict__ metaE,
    float2* __restrict__ metaS, float* __restrict__ blockpsum) {
  int wave = threadIdx.x >> 6, lane = threadIdx.x & 63;
  int t = blockIdx.x * 4 + wave;
  __shared__ float sprob[4][8];

  const float4* xr = (const float4*)(xmid + (size_t)t * DMODEL);
  const float4* wr = (const float4*)normw;
  float4 v[4];
  float ss = 0.f;
#pragma unroll
  for (int i = 0; i < 4; i++) {
    v[i] = xr[lane * 4 + i];
    ss += v[i].x * v[i].x + v[i].y * v[i].y + v[i].z * v[i].z + v[i].w * v[i].w;
  }
#pragma unroll
  for (int o = 32; o > 0; o >>= 1) ss += __shfl_xor(ss, o);
  float rstd = rsqrtf(ss / (float)DMODEL + 1e-6f);

  float part[8] = {0, 0, 0, 0, 0, 0, 0, 0};
#pragma unroll
  for (int i = 0; i < 4; i++) {
    float4 wv = wr[lane * 4 + i];
    float hv[4] = {v[i].x * rstd * wv.x, v[i].y * rstd * wv.y,
                   v[i].z * rstd * wv.z, v[i].w * rstd * wv.w};
#pragma unroll
    for (int j = 0; j < 4; j++) {
      int row = lane * 16 + i * 4 + j;
      const float4* rr = (const float4*)(rw + (size_t)row * NEXP);
      float4 a = rr[0], b = rr[1];
      part[0] += hv[j] * a.x; part[1] += hv[j] * a.y;
      part[2] += hv[j] * a.z; part[3] += hv[j] * a.w;
      part[4] += hv[j] * b.x; part[5] += hv[j] * b.y;
      part[6] += hv[j] * b.z; part[7] += hv[j] * b.w;
    }
  }
#pragma unroll
  for (int o = 1; o < 64; o <<= 1)
#pragma unroll
    for (int e = 0; e < 8; e++) part[e] += __shfl_xor(part[e], o);

  if (lane == 0) {
    float mx = -3.0e38f;
#pragma unroll
    for (int e = 0; e < 8; e++) mx = fmaxf(mx, part[e]);
    float probs[8], sum = 0.f;
#pragma unroll
    for (int e = 0; e < 8; e++) { probs[e] = __expf(part[e] - mx); sum += probs[e]; }
    float inv = 1.f / sum;
#pragma unroll
    for (int e = 0; e < 8; e++) { probs[e] *= inv; sprob[wave][e] = probs[e]; }
    int e0 = 0;
#pragma unroll
    for (int e = 1; e < 8; e++) if (part[e] > part[e0]) e0 = e;
    int e1 = (e0 == 0) ? 1 : 0;
#pragma unroll
    for (int e = 0; e < 8; e++) if (e != e0 && part[e] > part[e1]) e1 = e;
    metaE[t] = make_int2(e0, e1);
    metaS[t] = make_float2(probs[e0], probs[e1]);
  }
  __syncthreads();
  if (threadIdx.x < 8)
    blockpsum[blockIdx.x * 8 + threadIdx.x] =
        sprob[0][threadIdx.x] + sprob[1][threadIdx.x] +
        sprob[2][threadIdx.x] + sprob[3][threadIdx.x];
}

// ---------------- scatter: one block per expert, deterministic prefix sum ----
__global__ __launch_bounds__(256) void scatter_kernel(
    const int2* __restrict__ metaE, int* __restrict__ list,
    int* __restrict__ metaP, int* __restrict__ cnt) {
  int e = blockIdx.x;
  int tid = threadIdx.x, lane = tid & 63, w = tid >> 6;
  __shared__ int wsum[4];
  __shared__ int sbase;
  if (tid == 0) sbase = 0;
  __syncthreads();
  for (int c = 0; c < NTOK; c += 256) {
    int tok = c + tid;
    int2 me = metaE[tok];
    bool m0 = (me.x == e), m1 = (me.y == e);
    bool m = m0 || m1;
    unsigned long long mask = __ballot(m);
    int wpre = __popcll(mask & ((1ull << lane) - 1ull));
    if (lane == 0) wsum[w] = __popcll(mask);
    __syncthreads();
    int base0 = sbase;
    int pre = wpre;
    for (int i = 0; i < w; i++) pre += wsum[i];
    int tot = wsum[0] + wsum[1] + wsum[2] + wsum[3];
    if (m) {
      int pos = base0 + pre;
      list[e * NTOK + base0 + pre] = tok;
      metaP[tok * 2 + (m0 ? 0 : 1)] = pos;
    }
    __syncthreads();
    if (tid == 0) sbase = base0 + tot;
  }
  __syncthreads();
  if (tid == 0) cnt[e] = sbase;
}

// ---------------- finalize: base offsets + balancing loss + counts ----------
__global__ __launch_bounds__(256) void finalize_kernel(
    const int* __restrict__ cnt, const float* __restrict__ blockpsum,
    int* __restrict__ base, float* __restrict__ out_tail) {
  int tid = threadIdx.x;
  int e = tid & 7, slot = tid >> 3;  // 32 slots per expert
  float acc = 0.f;
  for (int i = slot; i < 1024; i += 32) acc += blockpsum[i * 8 + e];
  __shared__ float red[256];
  red[tid] = acc;
  __syncthreads();
  for (int s = 128; s >= 8; s >>= 1) {
    if (tid < s) red[tid] += red[tid + s];
    __syncthreads();
  }
  if (tid == 0) {
    int b = 0;
#pragma unroll
    for (int i = 0; i < 8; i++) { base[i] = b; b += cnt[i]; }
    base[8] = b;
    float loss = 0.f;
#pragma unroll
    for (int i = 0; i < 8; i++)
      loss += ((float)cnt[i] / (float)NPAIR) * (red[i] / (float)NTOK);
    out_tail[0] = loss * (float)NEXP;
#pragma unroll
    for (int i = 0; i < 8; i++) out_tail[1 + i] = (float)cnt[i];
  }
}

// ---------------- final combine ----------------
__global__ void combine_kernel(const float* __restrict__ xmid, const float* __restrict__ yv,
                               const int2* __restrict__ metaE, const int* __restrict__ metaP,
                               const float2* __restrict__ metaS,
                               const int* __restrict__ base, float* __restrict__ out) {
  int t = blockIdx.x, tid = threadIdx.x;
  int2 me = metaE[t];
  float2 sc = metaS[t];
  size_t s0 = (size_t)(base[me.x] + metaP[t * 2 + 0]) * DMODEL;
  size_t s1 = (size_t)(base[me.y] + metaP[t * 2 + 1]) * DMODEL;
  float4 a = ((const float4*)(xmid + (size_t)t * DMODEL))[tid];
  float4 y0 = ((const float4*)(yv + s0))[tid];
  float4 y1 = ((const float4*)(yv + s1))[tid];
  float4 o;
  o.x = a.x + sc.x * y0.x + sc.y * y1.x;
  o.y = a.y + sc.x * y0.y + sc.y * y1.y;
  o.z = a.z + sc.x * y0.z + sc.y * y1.z;
  o.w = a.w + sc.x * y0.w + sc.y * y1.w;
  ((float4*)(out + (size_t)t * DMODEL))[tid] = o;
}

// ---------------------------------------------------------------------------
extern "C" void kernel_launch(void* const* d_in, const int* in_sizes, int n_in,
                              void* d_out, int out_size, void* d_ws, size_t ws_size,
                              hipStream_t stream) {
  (void)in_sizes; (void)n_in; (void)out_size; (void)ws_size;
  const float* x    = (const float*)d_in[0];
  const int*   am   = (const int*)d_in[1];
  const float* anw  = (const float*)d_in[2];
  const float* wq   = (const float*)d_in[3];
  const float* wk   = (const float*)d_in[4];
  const float* wv   = (const float*)d_in[5];
  const float* wo   = (const float*)d_in[6];
  const float* mnw  = (const float*)d_in[7];
  const float* rw   = (const float*)d_in[8];
  const float* w1   = (const float*)d_in[9];
  const float* b1   = (const float*)d_in[10];
  const float* w2   = (const float*)d_in[11];
  const float* b2   = (const float*)d_in[12];
  float* out = (float*)d_out;
  char* ws = (char*)d_ws;

  f16* wqkvT = (f16*)(ws + OFF_WQKVT);
  f16* woT   = (f16*)(ws + OFF_WOT);
  f16* w1T   = (f16*)(ws + OFF_W1T);
  f16* w2T   = (f16*)(ws + OFF_W2T);
  f16* hattn = (f16*)(ws + OFF_HATTN);
  f16* qb    = (f16*)(ws + OFF_Q);
  f16* kb    = (f16*)(ws + OFF_K);
  f16* vtb   = (f16*)(ws + OFF_VT);
  f16* oc    = (f16*)(ws + OFF_OC);
  float* xmid = (float*)(ws + OFF_XMID);
  f16* hmlp  = (f16*)(ws + OFF_HMLP);
  f16* hid   = (f16*)(ws + OFF_HID);
  float* y   = (float*)(ws + OFF_Y);
  int* list  = (int*)(ws + OFF_LIST);
  int2* metaE = (int2*)(ws + OFF_METAE);
  int* metaP  = (int*)(ws + OFF_METAP);
  float2* metaS = (float2*)(ws + OFF_METAS);
  float* bpsum = (float*)(ws + OFF_BPSUM);
  int* cnt   = (int*)(ws + OFF_CNT);
  int* base  = (int*)(ws + OFF_BASE);

  dim3 tb(32, 8, 1);
  transpose_cast_kernel<<<dim3(32, 32, 1), tb, 0, stream>>>(wq, wqkvT, 1024, 1024);
  transpose_cast_kernel<<<dim3(32, 32, 1), tb, 0, stream>>>(wk, wqkvT + 1024 * 1024, 1024, 1024);
  transpose_cast_kernel<<<dim3(32, 32, 1), tb, 0, stream>>>(wv, wqkvT + 2 * 1024 * 1024, 1024, 1024);
  transpose_cast_kernel<<<dim3(32, 32, 1), tb, 0, stream>>>(wo, woT, 1024, 1024);
  transpose_cast_kernel<<<dim3(128, 32, 8), tb, 0, stream>>>(w1, w1T, 1024, 4096);
  transpose_cast_kernel<<<dim3(32, 128, 8), tb, 0, stream>>>(w2, w2T, 4096, 1024);

  rmsnorm_kernel<<<NTOK, 256, 0, stream>>>(x, anw, hattn);
  gemm_qkv_kernel<<<dim3(24, 32), 256, 0, stream>>>(hattn, wqkvT, qb, kb, vtb);
  attn_kernel<<<dim3(8, 32), 256, 0, stream>>>(qb, kb, vtb, am, oc);
  gemm_o_kernel<<<dim3(8, 32), 256, 0, stream>>>(oc, woT, x, xmid);
  rmsnorm_kernel<<<NTOK, 256, 0, stream>>>(xmid, mnw, hmlp);
  router_kernel<<<1024, 256, 0, stream>>>(xmid, mnw, rw, metaE, metaS, bpsum);
  scatter_kernel<<<8, 256, 0, stream>>>(metaE, list, metaP, cnt);
  finalize_kernel<<<1, 256, 0, stream>>>(cnt, bpsum, base, out + (size_t)NTOK * DMODEL);
  gemm_moe1_kernel<<<dim3(32, 32, 8), 256, 0, stream>>>(hmlp, w1T, b1, cnt, base, list, hid);
  gemm_moe2_kernel<<<dim3(8, 32, 8), 256, 0, stream>>>(hid, w2T, b2, cnt, base, y);
  combine_kernel<<<NTOK, 256, 0, stream>>>(xmid, y, metaE, metaP, metaS, base, out);
}

// Round 3
// 863.540 us; speedup vs baseline: 1.6479x; 1.0916x over previous
//
#include <hip/hip_runtime.h>

// ---------------------------------------------------------------------------
// PraxisBlock: rmsnorm -> QKV -> causal MHA -> O+residual -> rmsnorm ->
//              router top2/8 -> gathered expert FFN (gelu) -> combine
// All GEMMs: fp16 MFMA (v_mfma_f32_16x16x32_f16), fp32 accumulate.
// R1: router restructured — no global atomics (was 515us of XCD ping-pong).
// R2: attention re-tiled 256->64 q-rows/block, 1024 blocks, 32KB LDS
//     (was 82KB -> 1 block/CU, 6% occupancy, diagonal imbalance).
//     bh = blockIdx.x so XCD = bh%8 pins each head's K/V to one L2.
// ---------------------------------------------------------------------------

typedef _Float16 f16;
typedef _Float16 f16x8 __attribute__((ext_vector_type(8)));
typedef _Float16 f16x4v __attribute__((ext_vector_type(4)));
typedef float f32x4 __attribute__((ext_vector_type(4)));

#define DMODEL 1024
#define NHEAD  16
#define HDIM   64
#define NEXP   8
#define DFFN   4096
#define NBATCH 2
#define NSEQ   2048
#define NTOK   4096   // NBATCH*NSEQ
#define NPAIR  8192   // NTOK*2

// ---- workspace byte offsets (all 256-aligned) ----
#define OFF_WQKVT  0ull                  // 3*1024*1024 f16
#define OFF_WOT    6291456ull            // 1024*1024 f16
#define OFF_W1T    8388608ull            // 8*4096*1024 f16
#define OFF_W2T    75497472ull           // 8*1024*4096 f16
#define OFF_HATTN  142606336ull          // 4096*1024 f16
#define OFF_Q      150994944ull          // 32*2048*64 f16
#define OFF_K      159383552ull
#define OFF_VT     167772160ull
#define OFF_OC     176160768ull          // 4096*1024 f16
#define OFF_XMID   184549376ull          // 4096*1024 f32
#define OFF_HMLP   201326592ull          // 4096*1024 f16
#define OFF_HID    209715200ull          // 8192*4096 f16
#define OFF_Y      276824064ull          // 8192*1024 f32
#define OFF_LIST   310378496ull          // 8*4096 int
#define OFF_METAE  310509568ull          // 4096 int2
#define OFF_METAP  310542336ull          // 4096 int2
#define OFF_METAS  310575104ull          // 4096 float2
#define OFF_BPSUM  310607872ull          // 1024*8 float (per-block prob sums)
#define OFF_CNT    310640640ull          // 8 int
#define OFF_PSUM   310640704ull          // 8 float
#define OFF_BASE   310640768ull          // 9 int

__device__ __forceinline__ void ldsAsync16(const void* g, void* l) {
  __builtin_amdgcn_global_load_lds((const __attribute__((address_space(1))) void*)g,
                                   (__attribute__((address_space(3))) void*)l, 16, 0, 0);
}

// ---------------- transpose + cast fp32[R][C] -> fp16[C][R] ----------------
__global__ void transpose_cast_kernel(const float* __restrict__ src, f16* __restrict__ dst,
                                      int R, int C) {
  __shared__ float tile[32][33];
  const size_t zoff = (size_t)blockIdx.z * R * C;
  src += zoff; dst += zoff;
  int c0 = blockIdx.x * 32, r0 = blockIdx.y * 32;
  int tx = threadIdx.x, ty = threadIdx.y;
#pragma unroll
  for (int i = 0; i < 4; i++)
    tile[ty + i * 8][tx] = src[(size_t)(r0 + ty + i * 8) * C + c0 + tx];
  __syncthreads();
#pragma unroll
  for (int i = 0; i < 4; i++)
    dst[(size_t)(c0 + ty + i * 8) * R + r0 + tx] = (f16)tile[tx][ty + i * 8];
}

// ---------------- rmsnorm fp32 -> fp16 ----------------
__global__ void rmsnorm_kernel(const float* __restrict__ x, const float* __restrict__ w,
                               f16* __restrict__ out) {
  int t = blockIdx.x, tid = threadIdx.x;
  float4 v = ((const float4*)(x + (size_t)t * DMODEL))[tid];
  float ss = v.x * v.x + v.y * v.y + v.z * v.z + v.w * v.w;
#pragma unroll
  for (int o = 32; o > 0; o >>= 1) ss += __shfl_down(ss, o);
  __shared__ float red[4];
  if ((tid & 63) == 0) red[tid >> 6] = ss;
  __syncthreads();
  float tot = red[0] + red[1] + red[2] + red[3];
  float rstd = rsqrtf(tot / (float)DMODEL + 1e-6f);
  float4 wv = ((const float4*)w)[tid];
  f16x4v o4;
  o4[0] = (f16)(v.x * rstd * wv.x);
  o4[1] = (f16)(v.y * rstd * wv.y);
  o4[2] = (f16)(v.z * rstd * wv.z);
  o4[3] = (f16)(v.w * rstd * wv.w);
  *(f16x4v*)(out + (size_t)t * DMODEL + tid * 4) = o4;
}

// ---------------- shared 128x128xK MFMA core ----------------
template <class EPI>
__device__ __forceinline__ void gemm128(const f16* aP0, const f16* aP1, const f16* aP2, const f16* aP3,
                                        const f16* bP0, const f16* bP1, const f16* bP2, const f16* bP3,
                                        int K, EPI epi) {
  __shared__ __align__(16) f16 sA[128 * 64];
  __shared__ __align__(16) f16 sB[128 * 64];
  const int tid = threadIdx.x;
  const int lane = tid & 63, wave = tid >> 6;
  const int wm = (wave >> 1) * 64, wn = (wave & 1) * 64;
  const int q4 = lane >> 4, l15 = lane & 15;
  const f16* aP[4] = {aP0, aP1, aP2, aP3};
  const f16* bP[4] = {bP0, bP1, bP2, bP3};
  f32x4 zero = {0.f, 0.f, 0.f, 0.f};
  f32x4 acc[4][4];
#pragma unroll
  for (int i = 0; i < 4; i++)
#pragma unroll
    for (int j = 0; j < 4; j++) acc[i][j] = zero;

  for (int k0 = 0; k0 < K; k0 += 64) {
    __syncthreads();
#pragma unroll
    for (int i = 0; i < 4; i++) {
      ldsAsync16(aP[i] + k0, &sA[(i * 4 + wave) * 512]);
      ldsAsync16(bP[i] + k0, &sB[(i * 4 + wave) * 512]);
    }
    __syncthreads();
#pragma unroll
    for (int kk = 0; kk < 2; kk++) {
      f16x8 af[4], bf[4];
#pragma unroll
      for (int mi = 0; mi < 4; mi++)
        af[mi] = *(const f16x8*)&sA[(wm + mi * 16 + l15) * 64 + kk * 32 + q4 * 8];
#pragma unroll
      for (int ni = 0; ni < 4; ni++)
        bf[ni] = *(const f16x8*)&sB[(wn + ni * 16 + l15) * 64 + kk * 32 + q4 * 8];
#pragma unroll
      for (int mi = 0; mi < 4; mi++)
#pragma unroll
        for (int ni = 0; ni < 4; ni++)
          acc[mi][ni] = __builtin_amdgcn_mfma_f32_16x16x32_f16(af[mi], bf[ni], acc[mi][ni], 0, 0, 0);
    }
  }
#pragma unroll
  for (int mi = 0; mi < 4; mi++)
#pragma unroll
    for (int ni = 0; ni < 4; ni++)
#pragma unroll
      for (int r = 0; r < 4; r++)
        epi(wm + mi * 16 + q4 * 4 + r, wn + ni * 16 + l15, acc[mi][ni][r]);
}

// ---------------- QKV projection (N=3072 stacked) ----------------
__global__ __launch_bounds__(256, 2) void gemm_qkv_kernel(
    const f16* __restrict__ hA, const f16* __restrict__ wT,
    f16* __restrict__ qb, f16* __restrict__ kb, f16* __restrict__ vtb) {
  int mt = blockIdx.y, nt = blockIdx.x;
  int tid = threadIdx.x, lane = tid & 63, wave = tid >> 6;
  int kc = lane & 7, rs = lane >> 3;
  const f16 *a[4], *b[4];
#pragma unroll
  for (int i = 0; i < 4; i++) {
    int row = i * 32 + wave * 8 + rs;
    a[i] = hA + (size_t)(mt * 128 + row) * DMODEL + kc * 8;
    b[i] = wT + (size_t)(nt * 128 + row) * DMODEL + kc * 8;
  }
  int mB = mt * 128, nB = nt * 128;
  gemm128(a[0], a[1], a[2], a[3], b[0], b[1], b[2], b[3], DMODEL,
    [&](int r, int c, float v) {
      int m = mB + r, n = nB + c;
      int mat = n >> 10, nn = n & 1023;
      int h = nn >> 6, d = nn & 63;
      int bI = m >> 11, s = m & 2047;
      int bh = bI * NHEAD + h;
      f16 hv = (f16)v;
      if (mat == 0)      qb[((size_t)bh * NSEQ + s) * HDIM + d] = hv;
      else if (mat == 1) kb[((size_t)bh * NSEQ + s) * HDIM + d] = hv;
      else               vtb[((size_t)bh * HDIM + d) * NSEQ + s] = hv;
    });
}

// ---------------- O projection + residual ----------------
__global__ __launch_bounds__(256, 2) void gemm_o_kernel(
    const f16* __restrict__ oc, const f16* __restrict__ woT,
    const float* __restrict__ xin, float* __restrict__ xmid) {
  int mt = blockIdx.y, nt = blockIdx.x;
  int tid = threadIdx.x, lane = tid & 63, wave = tid >> 6;
  int kc = lane & 7, rs = lane >> 3;
  const f16 *a[4], *b[4];
#pragma unroll
  for (int i = 0; i < 4; i++) {
    int row = i * 32 + wave * 8 + rs;
    a[i] = oc + (size_t)(mt * 128 + row) * DMODEL + kc * 8;
    b[i] = woT + (size_t)(nt * 128 + row) * DMODEL + kc * 8;
  }
  int mB = mt * 128, nB = nt * 128;
  gemm128(a[0], a[1], a[2], a[3], b[0], b[1], b[2], b[3], DMODEL,
    [&](int r, int c, float v) {
      size_t idx = (size_t)(mB + r) * DMODEL + nB + c;
      xmid[idx] = xin[idx] + v;
    });
}

// ---------------- MoE expert GEMM 1: h -> gelu(h*w1+b1) ----------------
__global__ __launch_bounds__(256, 2) void gemm_moe1_kernel(
    const f16* __restrict__ hM, const f16* __restrict__ w1T, const float* __restrict__ b1,
    const int* __restrict__ cnt, const int* __restrict__ base, const int* __restrict__ list,
    f16* __restrict__ hid) {
  int e = blockIdx.z, mt = blockIdx.y, nt = blockIdx.x;
  int c_e = cnt[e];
  if (mt * 128 >= c_e) return;
  int tid = threadIdx.x, lane = tid & 63, wave = tid >> 6;
  int kc = lane & 7, rs = lane >> 3;
  const f16 *a[4], *b[4];
#pragma unroll
  for (int i = 0; i < 4; i++) {
    int row = i * 32 + wave * 8 + rs;
    int rr = mt * 128 + row; rr = rr < c_e ? rr : c_e - 1;
    int tok = list[e * NTOK + rr];
    a[i] = hM + (size_t)tok * DMODEL + kc * 8;
    b[i] = w1T + ((size_t)e * DFFN + nt * 128 + row) * DMODEL + kc * 8;
  }
  int rowBase = base[e] + mt * 128, nB = nt * 128, mLoc = mt * 128;
  gemm128(a[0], a[1], a[2], a[3], b[0], b[1], b[2], b[3], DMODEL,
    [&](int r, int c, float v) {
      if (mLoc + r < c_e) {
        float v2 = v + b1[e * DFFN + nB + c];
        float u = 1.5957691216057308f * (v2 + 0.044715f * v2 * v2 * v2); // 2*0.79788456*
        float th = 1.f - 2.f / (__expf(u) + 1.f);                        // tanh
        hid[(size_t)(rowBase + r) * DFFN + nB + c] = (f16)(0.5f * v2 * (1.f + th));
      }
    });
}

// ---------------- MoE expert GEMM 2: hid*w2+b2 -> y ----------------
__global__ __launch_bounds__(256, 2) void gemm_moe2_kernel(
    const f16* __restrict__ hid, const f16* __restrict__ w2T, const float* __restrict__ b2,
    const int* __restrict__ cnt, const int* __restrict__ base, float* __restrict__ y) {
  int e = blockIdx.z, mt = blockIdx.y, nt = blockIdx.x;
  int c_e = cnt[e];
  if (mt * 128 >= c_e) return;
  int tid = threadIdx.x, lane = tid & 63, wave = tid >> 6;
  int kc = lane & 7, rs = lane >> 3;
  int bse = base[e];
  const f16 *a[4], *b[4];
#pragma unroll
  for (int i = 0; i < 4; i++) {
    int row = i * 32 + wave * 8 + rs;
    int rr = mt * 128 + row; rr = rr < c_e ? rr : c_e - 1;
    a[i] = hid + (size_t)(bse + rr) * DFFN + kc * 8;
    b[i] = w2T + ((size_t)e * DMODEL + nt * 128 + row) * DFFN + kc * 8;
  }
  int nB = nt * 128, mLoc = mt * 128;
  gemm128(a[0], a[1], a[2], a[3], b[0], b[1], b[2], b[3], DFFN,
    [&](int r, int c, float v) {
      if (mLoc + r < c_e)
        y[(size_t)(bse + mLoc + r) * DMODEL + nB + c] = v + b2[e * DMODEL + nB + c];
    });
}

// ---------------- flash attention (causal + key mask) ----------------
// 64 q-rows per block, 4 waves x 16 q-rows. bh on blockIdx.x so each head's
// K/V stays on one XCD (XCD = linear_id % 8 = bh % 8).
__global__ __launch_bounds__(256, 4) void attn_kernel(
    const f16* __restrict__ qb, const f16* __restrict__ kb, const f16* __restrict__ vtb,
    const int* __restrict__ amask, f16* __restrict__ oc) {
  int bh = blockIdx.x, qt = blockIdx.y;
  int bI = bh >> 4, h = bh & 15;
  int qbase = qt * 64;
  int tid = threadIdx.x, lane = tid & 63, wave = tid >> 6;
  int q4 = lane >> 4, l15 = lane & 15;
  int kc = lane & 7, rs = lane >> 3;

  __shared__ __align__(16) f16 sQ[64 * 64];
  __shared__ __align__(16) f16 sK[64 * 64];
  __shared__ __align__(16) f16 sVT[64 * 64];
  __shared__ __align__(16) f16 sP[4][16 * 64];
  __shared__ int sMask[64];

  const f16* qBH = qb + (size_t)bh * NSEQ * HDIM;
  const f16* kBH = kb + (size_t)bh * NSEQ * HDIM;
  const f16* vBH = vtb + (size_t)bh * HDIM * NSEQ;

#pragma unroll
  for (int i = 0; i < 2; i++) {
    int row = i * 32 + wave * 8 + rs;  // 0..63
    ldsAsync16(qBH + (size_t)(qbase + row) * HDIM + kc * 8, &sQ[(i * 4 + wave) * 512]);
  }

  f32x4 zero = {0.f, 0.f, 0.f, 0.f};
  f32x4 accO[4];
  float mrow[4], lrow[4];
#pragma unroll
  for (int j = 0; j < 4; j++) { accO[j] = zero; mrow[j] = -3.0e38f; lrow[j] = 0.f; }

  f16* sPw = sP[wave];

  for (int kt = 0; kt <= qt; kt++) {
    int kb0 = kt * 64;
    bool diag = (kt == qt);
    __syncthreads();
#pragma unroll
    for (int i = 0; i < 2; i++) {
      int row = i * 32 + wave * 8 + rs;  // 0..63
      ldsAsync16(kBH + (size_t)(kb0 + row) * HDIM + kc * 8, &sK[(i * 4 + wave) * 512]);
      ldsAsync16(vBH + (size_t)row * NSEQ + kb0 + kc * 8, &sVT[(i * 4 + wave) * 512]);
    }
    if (tid < 64) sMask[tid] = amask[bI * NSEQ + kb0 + tid];
    __syncthreads();

    f32x4 accS[4];
#pragma unroll
    for (int j = 0; j < 4; j++) accS[j] = zero;
#pragma unroll
    for (int kk = 0; kk < 2; kk++) {
      f16x8 af = *(const f16x8*)&sQ[(wave * 16 + l15) * 64 + kk * 32 + q4 * 8];
      f16x8 bf[4];
#pragma unroll
      for (int nj = 0; nj < 4; nj++)
        bf[nj] = *(const f16x8*)&sK[(nj * 16 + l15) * 64 + kk * 32 + q4 * 8];
#pragma unroll
      for (int nj = 0; nj < 4; nj++)
        accS[nj] = __builtin_amdgcn_mfma_f32_16x16x32_f16(af, bf[nj], accS[nj], 0, 0, 0);
    }
    bool mok[4];
    int gk[4];
#pragma unroll
    for (int nj = 0; nj < 4; nj++) {
      gk[nj] = nj * 16 + l15;
      mok[nj] = sMask[gk[nj]] > 0;
    }
#pragma unroll
    for (int r = 0; r < 4; r++) {
      int lq = wave * 16 + q4 * 4 + r;  // local q row 0..63; global gq = qbase+lq
      float rm = -3.0e38f;
#pragma unroll
      for (int nj = 0; nj < 4; nj++) {
        float s = accS[nj][r] * 0.125f;
        bool ok = mok[nj] && (!diag || gk[nj] <= lq);
        s = ok ? s : -1.0e9f;
        accS[nj][r] = s;
        rm = fmaxf(rm, s);
      }
#pragma unroll
      for (int o = 1; o < 16; o <<= 1) rm = fmaxf(rm, __shfl_xor(rm, o));
      float mold = mrow[r];
      float mnew = fmaxf(mold, rm);
      float alpha = __expf(mold - mnew);
      float rsum = 0.f;
#pragma unroll
      for (int nj = 0; nj < 4; nj++) {
        float p = __expf(accS[nj][r] - mnew);
        rsum += p;
        sPw[(q4 * 4 + r) * 64 + nj * 16 + l15] = (f16)p;
      }
#pragma unroll
      for (int o = 1; o < 16; o <<= 1) rsum += __shfl_xor(rsum, o);
      lrow[r] = lrow[r] * alpha + rsum;
      mrow[r] = mnew;
#pragma unroll
      for (int dj = 0; dj < 4; dj++) accO[dj][r] *= alpha;
    }
    // PV (sP is per-wave private; compiler's lgkmcnt covers write->read)
#pragma unroll
    for (int kk = 0; kk < 2; kk++) {
      f16x8 pf = *(const f16x8*)&sPw[l15 * 64 + kk * 32 + q4 * 8];
      f16x8 vf[4];
#pragma unroll
      for (int dj = 0; dj < 4; dj++)
        vf[dj] = *(const f16x8*)&sVT[(dj * 16 + l15) * 64 + kk * 32 + q4 * 8];
#pragma unroll
      for (int dj = 0; dj < 4; dj++)
        accO[dj] = __builtin_amdgcn_mfma_f32_16x16x32_f16(pf, vf[dj], accO[dj], 0, 0, 0);
    }
  }
  // epilogue: divide by l, scatter to o_concat[token][h*64+d]
#pragma unroll
  for (int r = 0; r < 4; r++) {
    float inv = 1.f / lrow[r];
    int s = qbase + wave * 16 + q4 * 4 + r;
    size_t rowoff = ((size_t)bI * NSEQ + s) * DMODEL + h * HDIM;
#pragma unroll
    for (int dj = 0; dj < 4; dj++)
      oc[rowoff + dj * 16 + l15] = (f16)(accO[dj][r] * inv);
  }
}

// ---------------- router: wave-per-token, NO global atomics ----------------
__global__ __launch_bounds__(256) void router_kernel(
    const float* __restrict__ xmid, const float* __restrict__ normw,
    const float* __restrict__ rw, int2* __restrict__ metaE,
    float2* __restrict__ metaS, float* __restrict__ blockpsum) {
  int wave = threadIdx.x >> 6, lane = threadIdx.x & 63;
  int t = blockIdx.x * 4 + wave;
  __shared__ float sprob[4][8];

  const float4* xr = (const float4*)(xmid + (size_t)t * DMODEL);
  const float4* wr = (const float4*)normw;
  float4 v[4];
  float ss = 0.f;
#pragma unroll
  for (int i = 0; i < 4; i++) {
    v[i] = xr[lane * 4 + i];
    ss += v[i].x * v[i].x + v[i].y * v[i].y + v[i].z * v[i].z + v[i].w * v[i].w;
  }
#pragma unroll
  for (int o = 32; o > 0; o >>= 1) ss += __shfl_xor(ss, o);
  float rstd = rsqrtf(ss / (float)DMODEL + 1e-6f);

  float part[8] = {0, 0, 0, 0, 0, 0, 0, 0};
#pragma unroll
  for (int i = 0; i < 4; i++) {
    float4 wv = wr[lane * 4 + i];
    float hv[4] = {v[i].x * rstd * wv.x, v[i].y * rstd * wv.y,
                   v[i].z * rstd * wv.z, v[i].w * rstd * wv.w};
#pragma unroll
    for (int j = 0; j < 4; j++) {
      int row = lane * 16 + i * 4 + j;
      const float4* rr = (const float4*)(rw + (size_t)row * NEXP);
      float4 a = rr[0], b = rr[1];
      part[0] += hv[j] * a.x; part[1] += hv[j] * a.y;
      part[2] += hv[j] * a.z; part[3] += hv[j] * a.w;
      part[4] += hv[j] * b.x; part[5] += hv[j] * b.y;
      part[6] += hv[j] * b.z; part[7] += hv[j] * b.w;
    }
  }
#pragma unroll
  for (int o = 1; o < 64; o <<= 1)
#pragma unroll
    for (int e = 0; e < 8; e++) part[e] += __shfl_xor(part[e], o);

  if (lane == 0) {
    float mx = -3.0e38f;
#pragma unroll
    for (int e = 0; e < 8; e++) mx = fmaxf(mx, part[e]);
    float probs[8], sum = 0.f;
#pragma unroll
    for (int e = 0; e < 8; e++) { probs[e] = __expf(part[e] - mx); sum += probs[e]; }
    float inv = 1.f / sum;
#pragma unroll
    for (int e = 0; e < 8; e++) { probs[e] *= inv; sprob[wave][e] = probs[e]; }
    int e0 = 0;
#pragma unroll
    for (int e = 1; e < 8; e++) if (part[e] > part[e0]) e0 = e;
    int e1 = (e0 == 0) ? 1 : 0;
#pragma unroll
    for (int e = 0; e < 8; e++) if (e != e0 && part[e] > part[e1]) e1 = e;
    metaE[t] = make_int2(e0, e1);
    metaS[t] = make_float2(probs[e0], probs[e1]);
  }
  __syncthreads();
  if (threadIdx.x < 8)
    blockpsum[blockIdx.x * 8 + threadIdx.x] =
        sprob[0][threadIdx.x] + sprob[1][threadIdx.x] +
        sprob[2][threadIdx.x] + sprob[3][threadIdx.x];
}

// ---------------- scatter: one block per expert, deterministic prefix sum ----
__global__ __launch_bounds__(256) void scatter_kernel(
    const int2* __restrict__ metaE, int* __restrict__ list,
    int* __restrict__ metaP, int* __restrict__ cnt) {
  int e = blockIdx.x;
  int tid = threadIdx.x, lane = tid & 63, w = tid >> 6;
  __shared__ int wsum[4];
  __shared__ int sbase;
  if (tid == 0) sbase = 0;
  __syncthreads();
  for (int c = 0; c < NTOK; c += 256) {
    int tok = c + tid;
    int2 me = metaE[tok];
    bool m0 = (me.x == e), m1 = (me.y == e);
    bool m = m0 || m1;
    unsigned long long mask = __ballot(m);
    int wpre = __popcll(mask & ((1ull << lane) - 1ull));
    if (lane == 0) wsum[w] = __popcll(mask);
    __syncthreads();
    int base0 = sbase;
    int pre = wpre;
    for (int i = 0; i < w; i++) pre += wsum[i];
    int tot = wsum[0] + wsum[1] + wsum[2] + wsum[3];
    if (m) {
      int pos = base0 + pre;
      list[e * NTOK + base0 + pre] = tok;
      metaP[tok * 2 + (m0 ? 0 : 1)] = pos;
    }
    __syncthreads();
    if (tid == 0) sbase = base0 + tot;
  }
  __syncthreads();
  if (tid == 0) cnt[e] = sbase;
}

// ---------------- finalize: base offsets + balancing loss + counts ----------
__global__ __launch_bounds__(256) void finalize_kernel(
    const int* __restrict__ cnt, const float* __restrict__ blockpsum,
    int* __restrict__ base, float* __restrict__ out_tail) {
  int tid = threadIdx.x;
  int e = tid & 7, slot = tid >> 3;  // 32 slots per expert
  float acc = 0.f;
  for (int i = slot; i < 1024; i += 32) acc += blockpsum[i * 8 + e];
  __shared__ float red[256];
  red[tid] = acc;
  __syncthreads();
  for (int s = 128; s >= 8; s >>= 1) {
    if (tid < s) red[tid] += red[tid + s];
    __syncthreads();
  }
  if (tid == 0) {
    int b = 0;
#pragma unroll
    for (int i = 0; i < 8; i++) { base[i] = b; b += cnt[i]; }
    base[8] = b;
    float loss = 0.f;
#pragma unroll
    for (int i = 0; i < 8; i++)
      loss += ((float)cnt[i] / (float)NPAIR) * (red[i] / (float)NTOK);
    out_tail[0] = loss * (float)NEXP;
#pragma unroll
    for (int i = 0; i < 8; i++) out_tail[1 + i] = (float)cnt[i];
  }
}

// ---------------- final combine ----------------
__global__ void combine_kernel(const float* __restrict__ xmid, const float* __restrict__ yv,
                               const int2* __restrict__ metaE, const int* __restrict__ metaP,
                               const float2* __restrict__ metaS,
                               const int* __restrict__ base, float* __restrict__ out) {
  int t = blockIdx.x, tid = threadIdx.x;
  int2 me = metaE[t];
  float2 sc = metaS[t];
  size_t s0 = (size_t)(base[me.x] + metaP[t * 2 + 0]) * DMODEL;
  size_t s1 = (size_t)(base[me.y] + metaP[t * 2 + 1]) * DMODEL;
  float4 a = ((const float4*)(xmid + (size_t)t * DMODEL))[tid];
  float4 y0 = ((const float4*)(yv + s0))[tid];
  float4 y1 = ((const float4*)(yv + s1))[tid];
  float4 o;
  o.x = a.x + sc.x * y0.x + sc.y * y1.x;
  o.y = a.y + sc.x * y0.y + sc.y * y1.y;
  o.z = a.z + sc.x * y0.z + sc.y * y1.z;
  o.w = a.w + sc.x * y0.w + sc.y * y1.w;
  ((float4*)(out + (size_t)t * DMODEL))[tid] = o;
}

// ---------------------------------------------------------------------------
extern "C" void kernel_launch(void* const* d_in, const int* in_sizes, int n_in,
                              void* d_out, int out_size, void* d_ws, size_t ws_size,
                              hipStream_t stream) {
  (void)in_sizes; (void)n_in; (void)out_size; (void)ws_size;
  const float* x    = (const float*)d_in[0];
  const int*   am   = (const int*)d_in[1];
  const float* anw  = (const float*)d_in[2];
  const float* wq   = (const float*)d_in[3];
  const float* wk   = (const float*)d_in[4];
  const float* wv   = (const float*)d_in[5];
  const float* wo   = (const float*)d_in[6];
  const float* mnw  = (const float*)d_in[7];
  const float* rw   = (const float*)d_in[8];
  const float* w1   = (const float*)d_in[9];
  const float* b1   = (const float*)d_in[10];
  const float* w2   = (const float*)d_in[11];
  const float* b2   = (const float*)d_in[12];
  float* out = (float*)d_out;
  char* ws = (char*)d_ws;

  f16* wqkvT = (f16*)(ws + OFF_WQKVT);
  f16* woT   = (f16*)(ws + OFF_WOT);
  f16* w1T   = (f16*)(ws + OFF_W1T);
  f16* w2T   = (f16*)(ws + OFF_W2T);
  f16* hattn = (f16*)(ws + OFF_HATTN);
  f16* qb    = (f16*)(ws + OFF_Q);
  f16* kb    = (f16*)(ws + OFF_K);
  f16* vtb   = (f16*)(ws + OFF_VT);
  f16* oc    = (f16*)(ws + OFF_OC);
  float* xmid = (float*)(ws + OFF_XMID);
  f16* hmlp  = (f16*)(ws + OFF_HMLP);
  f16* hid   = (f16*)(ws + OFF_HID);
  float* y   = (float*)(ws + OFF_Y);
  int* list  = (int*)(ws + OFF_LIST);
  int2* metaE = (int2*)(ws + OFF_METAE);
  int* metaP  = (int*)(ws + OFF_METAP);
  float2* metaS = (float2*)(ws + OFF_METAS);
  float* bpsum = (float*)(ws + OFF_BPSUM);
  int* cnt   = (int*)(ws + OFF_CNT);
  int* base  = (int*)(ws + OFF_BASE);

  dim3 tb(32, 8, 1);
  transpose_cast_kernel<<<dim3(32, 32, 1), tb, 0, stream>>>(wq, wqkvT, 1024, 1024);
  transpose_cast_kernel<<<dim3(32, 32, 1), tb, 0, stream>>>(wk, wqkvT + 1024 * 1024, 1024, 1024);
  transpose_cast_kernel<<<dim3(32, 32, 1), tb, 0, stream>>>(wv, wqkvT + 2 * 1024 * 1024, 1024, 1024);
  transpose_cast_kernel<<<dim3(32, 32, 1), tb, 0, stream>>>(wo, woT, 1024, 1024);
  transpose_cast_kernel<<<dim3(128, 32, 8), tb, 0, stream>>>(w1, w1T, 1024, 4096);
  transpose_cast_kernel<<<dim3(32, 128, 8), tb, 0, stream>>>(w2, w2T, 4096, 1024);

  rmsnorm_kernel<<<NTOK, 256, 0, stream>>>(x, anw, hattn);
  gemm_qkv_kernel<<<dim3(24, 32), 256, 0, stream>>>(hattn, wqkvT, qb, kb, vtb);
  attn_kernel<<<dim3(32, 32), 256, 0, stream>>>(qb, kb, vtb, am, oc);
  gemm_o_kernel<<<dim3(8, 32), 256, 0, stream>>>(oc, woT, x, xmid);
  rmsnorm_kernel<<<NTOK, 256, 0, stream>>>(xmid, mnw, hmlp);
  router_kernel<<<1024, 256, 0, stream>>>(xmid, mnw, rw, metaE, metaS, bpsum);
  scatter_kernel<<<8, 256, 0, stream>>>(metaE, list, metaP, cnt);
  finalize_kernel<<<1, 256, 0, stream>>>(cnt, bpsum, base, out + (size_t)NTOK * DMODEL);
  gemm_moe1_kernel<<<dim3(32, 32, 8), 256, 0, stream>>>(hmlp, w1T, b1, cnt, base, list, hid);
  gemm_moe2_kernel<<<dim3(8, 32, 8), 256, 0, stream>>>(hid, w2T, b2, cnt, base, y);
  combine_kernel<<<NTOK, 256, 0, stream>>>(xmid, y, metaE, metaP, metaS, base, out);
}

// Round 4
// 835.763 us; speedup vs baseline: 1.7027x; 1.0332x over previous
//
#include <hip/hip_runtime.h>

// ---------------------------------------------------------------------------
// PraxisBlock: rmsnorm -> QKV -> causal MHA -> O+residual -> rmsnorm ->
//              router top2/8 -> gathered expert FFN (gelu) -> combine
// All GEMMs: fp16 MFMA (v_mfma_f32_16x16x32_f16), fp32 accumulate.
// R1: router restructured — no global atomics (was 515us of XCD ping-pong).
// R2: attention re-tiled 64 q-rows/block, 1024 blocks, 32KB LDS.
// R3: XOR-swizzled LDS in gemm128 (lane fetches global chunk kc^rs, reads use
//     j^(row&7) -> bank conflicts ~0; was 2.75e7 cycles on moe2) and
//     split-K x2 for moe2 (512 -> 1024 blocks; partials y/y2, y2 reuses the
//     dead hattn/q/k/vt region; summed in combine).
// ---------------------------------------------------------------------------

typedef _Float16 f16;
typedef _Float16 f16x8 __attribute__((ext_vector_type(8)));
typedef _Float16 f16x4v __attribute__((ext_vector_type(4)));
typedef float f32x4 __attribute__((ext_vector_type(4)));

#define DMODEL 1024
#define NHEAD  16
#define HDIM   64
#define NEXP   8
#define DFFN   4096
#define NBATCH 2
#define NSEQ   2048
#define NTOK   4096   // NBATCH*NSEQ
#define NPAIR  8192   // NTOK*2

// ---- workspace byte offsets (all 256-aligned) ----
#define OFF_WQKVT  0ull                  // 3*1024*1024 f16
#define OFF_WOT    6291456ull            // 1024*1024 f16
#define OFF_W1T    8388608ull            // 8*4096*1024 f16
#define OFF_W2T    75497472ull           // 8*1024*4096 f16
#define OFF_HATTN  142606336ull          // 4096*1024 f16   (dead after gemm_o; y2 reuses)
#define OFF_Q      150994944ull          // 32*2048*64 f16
#define OFF_K      159383552ull
#define OFF_VT     167772160ull
#define OFF_OC     176160768ull          // 4096*1024 f16
#define OFF_XMID   184549376ull          // 4096*1024 f32
#define OFF_HMLP   201326592ull          // 4096*1024 f16
#define OFF_HID    209715200ull          // 8192*4096 f16
#define OFF_Y      276824064ull          // 8192*1024 f32 (split-K half 0, +bias)
#define OFF_Y2     OFF_HATTN             // 8192*1024 f32 (split-K half 1) — hattn/q/k/vt dead by then
#define OFF_LIST   310378496ull          // 8*4096 int
#define OFF_METAE  310509568ull          // 4096 int2
#define OFF_METAP  310542336ull          // 4096 int2
#define OFF_METAS  310575104ull          // 4096 float2
#define OFF_BPSUM  310607872ull          // 1024*8 float (per-block prob sums)
#define OFF_CNT    310640640ull          // 8 int
#define OFF_PSUM   310640704ull          // 8 float
#define OFF_BASE   310640768ull          // 9 int

__device__ __forceinline__ void ldsAsync16(const void* g, void* l) {
  __builtin_amdgcn_global_load_lds((const __attribute__((address_space(1))) void*)g,
                                   (__attribute__((address_space(3))) void*)l, 16, 0, 0);
}

// ---------------- transpose + cast fp32[R][C] -> fp16[C][R] ----------------
__global__ void transpose_cast_kernel(const float* __restrict__ src, f16* __restrict__ dst,
                                      int R, int C) {
  __shared__ float tile[32][33];
  const size_t zoff = (size_t)blockIdx.z * R * C;
  src += zoff; dst += zoff;
  int c0 = blockIdx.x * 32, r0 = blockIdx.y * 32;
  int tx = threadIdx.x, ty = threadIdx.y;
#pragma unroll
  for (int i = 0; i < 4; i++)
    tile[ty + i * 8][tx] = src[(size_t)(r0 + ty + i * 8) * C + c0 + tx];
  __syncthreads();
#pragma unroll
  for (int i = 0; i < 4; i++)
    dst[(size_t)(c0 + ty + i * 8) * R + r0 + tx] = (f16)tile[tx][ty + i * 8];
}

// ---------------- rmsnorm fp32 -> fp16 ----------------
__global__ void rmsnorm_kernel(const float* __restrict__ x, const float* __restrict__ w,
                               f16* __restrict__ out) {
  int t = blockIdx.x, tid = threadIdx.x;
  float4 v = ((const float4*)(x + (size_t)t * DMODEL))[tid];
  float ss = v.x * v.x + v.y * v.y + v.z * v.z + v.w * v.w;
#pragma unroll
  for (int o = 32; o > 0; o >>= 1) ss += __shfl_down(ss, o);
  __shared__ float red[4];
  if ((tid & 63) == 0) red[tid >> 6] = ss;
  __syncthreads();
  float tot = red[0] + red[1] + red[2] + red[3];
  float rstd = rsqrtf(tot / (float)DMODEL + 1e-6f);
  float4 wv = ((const float4*)w)[tid];
  f16x4v o4;
  o4[0] = (f16)(v.x * rstd * wv.x);
  o4[1] = (f16)(v.y * rstd * wv.y);
  o4[2] = (f16)(v.z * rstd * wv.z);
  o4[3] = (f16)(v.w * rstd * wv.w);
  *(f16x4v*)(out + (size_t)t * DMODEL + tid * 4) = o4;
}

// ---------------- shared 128x128xK MFMA core (XOR-swizzled LDS) ----------
// Staging contract: callers must point lane (kc=lane&7, rs=lane>>3) at global
// column chunk (kc ^ rs)*8 of its row, NOT kc*8. LDS[row][c] then holds global
// chunk c^(row&7); fragment reads below un-swizzle with j^(row&7).
template <class EPI>
__device__ __forceinline__ void gemm128(const f16* aP0, const f16* aP1, const f16* aP2, const f16* aP3,
                                        const f16* bP0, const f16* bP1, const f16* bP2, const f16* bP3,
                                        int K, EPI epi) {
  __shared__ __align__(16) f16 sA[128 * 64];
  __shared__ __align__(16) f16 sB[128 * 64];
  const int tid = threadIdx.x;
  const int lane = tid & 63, wave = tid >> 6;
  const int wm = (wave >> 1) * 64, wn = (wave & 1) * 64;
  const int q4 = lane >> 4, l15 = lane & 15;
  const int sw = lane & 7;  // == l15 & 7 == row&7 for fragment rows
  const f16* aP[4] = {aP0, aP1, aP2, aP3};
  const f16* bP[4] = {bP0, bP1, bP2, bP3};
  f32x4 zero = {0.f, 0.f, 0.f, 0.f};
  f32x4 acc[4][4];
#pragma unroll
  for (int i = 0; i < 4; i++)
#pragma unroll
    for (int j = 0; j < 4; j++) acc[i][j] = zero;

  for (int k0 = 0; k0 < K; k0 += 64) {
    __syncthreads();
#pragma unroll
    for (int i = 0; i < 4; i++) {
      ldsAsync16(aP[i] + k0, &sA[(i * 4 + wave) * 512]);
      ldsAsync16(bP[i] + k0, &sB[(i * 4 + wave) * 512]);
    }
    __syncthreads();
#pragma unroll
    for (int kk = 0; kk < 2; kk++) {
      f16x8 af[4], bf[4];
      int jx = ((kk * 4 + q4) ^ sw) * 8;
#pragma unroll
      for (int mi = 0; mi < 4; mi++)
        af[mi] = *(const f16x8*)&sA[(wm + mi * 16 + l15) * 64 + jx];
#pragma unroll
      for (int ni = 0; ni < 4; ni++)
        bf[ni] = *(const f16x8*)&sB[(wn + ni * 16 + l15) * 64 + jx];
#pragma unroll
      for (int mi = 0; mi < 4; mi++)
#pragma unroll
        for (int ni = 0; ni < 4; ni++)
          acc[mi][ni] = __builtin_amdgcn_mfma_f32_16x16x32_f16(af[mi], bf[ni], acc[mi][ni], 0, 0, 0);
    }
  }
#pragma unroll
  for (int mi = 0; mi < 4; mi++)
#pragma unroll
    for (int ni = 0; ni < 4; ni++)
#pragma unroll
      for (int r = 0; r < 4; r++)
        epi(wm + mi * 16 + q4 * 4 + r, wn + ni * 16 + l15, acc[mi][ni][r]);
}

// ---------------- QKV projection (N=3072 stacked) ----------------
__global__ __launch_bounds__(256, 2) void gemm_qkv_kernel(
    const f16* __restrict__ hA, const f16* __restrict__ wT,
    f16* __restrict__ qb, f16* __restrict__ kb, f16* __restrict__ vtb) {
  int mt = blockIdx.y, nt = blockIdx.x;
  int tid = threadIdx.x, lane = tid & 63, wave = tid >> 6;
  int kc = lane & 7, rs = lane >> 3;
  int kcs = (kc ^ rs) * 8;  // swizzled column chunk
  const f16 *a[4], *b[4];
#pragma unroll
  for (int i = 0; i < 4; i++) {
    int row = i * 32 + wave * 8 + rs;
    a[i] = hA + (size_t)(mt * 128 + row) * DMODEL + kcs;
    b[i] = wT + (size_t)(nt * 128 + row) * DMODEL + kcs;
  }
  int mB = mt * 128, nB = nt * 128;
  gemm128(a[0], a[1], a[2], a[3], b[0], b[1], b[2], b[3], DMODEL,
    [&](int r, int c, float v) {
      int m = mB + r, n = nB + c;
      int mat = n >> 10, nn = n & 1023;
      int h = nn >> 6, d = nn & 63;
      int bI = m >> 11, s = m & 2047;
      int bh = bI * NHEAD + h;
      f16 hv = (f16)v;
      if (mat == 0)      qb[((size_t)bh * NSEQ + s) * HDIM + d] = hv;
      else if (mat == 1) kb[((size_t)bh * NSEQ + s) * HDIM + d] = hv;
      else               vtb[((size_t)bh * HDIM + d) * NSEQ + s] = hv;
    });
}

// ---------------- O projection + residual ----------------
__global__ __launch_bounds__(256, 2) void gemm_o_kernel(
    const f16* __restrict__ oc, const f16* __restrict__ woT,
    const float* __restrict__ xin, float* __restrict__ xmid) {
  int mt = blockIdx.y, nt = blockIdx.x;
  int tid = threadIdx.x, lane = tid & 63, wave = tid >> 6;
  int kc = lane & 7, rs = lane >> 3;
  int kcs = (kc ^ rs) * 8;
  const f16 *a[4], *b[4];
#pragma unroll
  for (int i = 0; i < 4; i++) {
    int row = i * 32 + wave * 8 + rs;
    a[i] = oc + (size_t)(mt * 128 + row) * DMODEL + kcs;
    b[i] = woT + (size_t)(nt * 128 + row) * DMODEL + kcs;
  }
  int mB = mt * 128, nB = nt * 128;
  gemm128(a[0], a[1], a[2], a[3], b[0], b[1], b[2], b[3], DMODEL,
    [&](int r, int c, float v) {
      size_t idx = (size_t)(mB + r) * DMODEL + nB + c;
      xmid[idx] = xin[idx] + v;
    });
}

// ---------------- MoE expert GEMM 1: h -> gelu(h*w1+b1) ----------------
__global__ __launch_bounds__(256, 2) void gemm_moe1_kernel(
    const f16* __restrict__ hM, const f16* __restrict__ w1T, const float* __restrict__ b1,
    const int* __restrict__ cnt, const int* __restrict__ base, const int* __restrict__ list,
    f16* __restrict__ hid) {
  int e = blockIdx.z, mt = blockIdx.y, nt = blockIdx.x;
  int c_e = cnt[e];
  if (mt * 128 >= c_e) return;
  int tid = threadIdx.x, lane = tid & 63, wave = tid >> 6;
  int kc = lane & 7, rs = lane >> 3;
  int kcs = (kc ^ rs) * 8;
  const f16 *a[4], *b[4];
#pragma unroll
  for (int i = 0; i < 4; i++) {
    int row = i * 32 + wave * 8 + rs;
    int rr = mt * 128 + row; rr = rr < c_e ? rr : c_e - 1;
    int tok = list[e * NTOK + rr];
    a[i] = hM + (size_t)tok * DMODEL + kcs;
    b[i] = w1T + ((size_t)e * DFFN + nt * 128 + row) * DMODEL + kcs;
  }
  int rowBase = base[e] + mt * 128, nB = nt * 128, mLoc = mt * 128;
  gemm128(a[0], a[1], a[2], a[3], b[0], b[1], b[2], b[3], DMODEL,
    [&](int r, int c, float v) {
      if (mLoc + r < c_e) {
        float v2 = v + b1[e * DFFN + nB + c];
        float u = 1.5957691216057308f * (v2 + 0.044715f * v2 * v2 * v2); // 2*0.79788456*
        float th = 1.f - 2.f / (__expf(u) + 1.f);                        // tanh
        hid[(size_t)(rowBase + r) * DFFN + nB + c] = (f16)(0.5f * v2 * (1.f + th));
      }
    });
}

// ---------------- MoE expert GEMM 2: hid*w2+b2 -> y (split-K x2) ----------
__global__ __launch_bounds__(256, 2) void gemm_moe2_kernel(
    const f16* __restrict__ hid, const f16* __restrict__ w2T, const float* __restrict__ b2,
    const int* __restrict__ cnt, const int* __restrict__ base,
    float* __restrict__ y, float* __restrict__ y2) {
  int z = blockIdx.z, e = z >> 1, kh = z & 1;
  int mt = blockIdx.y, nt = blockIdx.x;
  int c_e = cnt[e];
  if (mt * 128 >= c_e) return;
  int tid = threadIdx.x, lane = tid & 63, wave = tid >> 6;
  int kc = lane & 7, rs = lane >> 3;
  int kcs = (kc ^ rs) * 8 + kh * 2048;
  int bse = base[e];
  const f16 *a[4], *b[4];
#pragma unroll
  for (int i = 0; i < 4; i++) {
    int row = i * 32 + wave * 8 + rs;
    int rr = mt * 128 + row; rr = rr < c_e ? rr : c_e - 1;
    a[i] = hid + (size_t)(bse + rr) * DFFN + kcs;
    b[i] = w2T + ((size_t)e * DMODEL + nt * 128 + row) * DFFN + kcs;
  }
  int nB = nt * 128, mLoc = mt * 128;
  float* yo = kh ? y2 : y;
  gemm128(a[0], a[1], a[2], a[3], b[0], b[1], b[2], b[3], 2048,
    [&](int r, int c, float v) {
      if (mLoc + r < c_e) {
        float bias = kh ? 0.f : b2[e * DMODEL + nB + c];
        yo[(size_t)(bse + mLoc + r) * DMODEL + nB + c] = v + bias;
      }
    });
}

// ---------------- flash attention (causal + key mask) ----------------
// 64 q-rows per block, 4 waves x 16 q-rows. bh on blockIdx.x so each head's
// K/V stays on one XCD (XCD = linear_id % 8 = bh % 8).
__global__ __launch_bounds__(256, 4) void attn_kernel(
    const f16* __restrict__ qb, const f16* __restrict__ kb, const f16* __restrict__ vtb,
    const int* __restrict__ amask, f16* __restrict__ oc) {
  int bh = blockIdx.x, qt = blockIdx.y;
  int bI = bh >> 4, h = bh & 15;
  int qbase = qt * 64;
  int tid = threadIdx.x, lane = tid & 63, wave = tid >> 6;
  int q4 = lane >> 4, l15 = lane & 15;
  int kc = lane & 7, rs = lane >> 3;

  __shared__ __align__(16) f16 sQ[64 * 64];
  __shared__ __align__(16) f16 sK[64 * 64];
  __shared__ __align__(16) f16 sVT[64 * 64];
  __shared__ __align__(16) f16 sP[4][16 * 64];
  __shared__ int sMask[64];

  const f16* qBH = qb + (size_t)bh * NSEQ * HDIM;
  const f16* kBH = kb + (size_t)bh * NSEQ * HDIM;
  const f16* vBH = vtb + (size_t)bh * HDIM * NSEQ;

#pragma unroll
  for (int i = 0; i < 2; i++) {
    int row = i * 32 + wave * 8 + rs;  // 0..63
    ldsAsync16(qBH + (size_t)(qbase + row) * HDIM + kc * 8, &sQ[(i * 4 + wave) * 512]);
  }

  f32x4 zero = {0.f, 0.f, 0.f, 0.f};
  f32x4 accO[4];
  float mrow[4], lrow[4];
#pragma unroll
  for (int j = 0; j < 4; j++) { accO[j] = zero; mrow[j] = -3.0e38f; lrow[j] = 0.f; }

  f16* sPw = sP[wave];

  for (int kt = 0; kt <= qt; kt++) {
    int kb0 = kt * 64;
    bool diag = (kt == qt);
    __syncthreads();
#pragma unroll
    for (int i = 0; i < 2; i++) {
      int row = i * 32 + wave * 8 + rs;  // 0..63
      ldsAsync16(kBH + (size_t)(kb0 + row) * HDIM + kc * 8, &sK[(i * 4 + wave) * 512]);
      ldsAsync16(vBH + (size_t)row * NSEQ + kb0 + kc * 8, &sVT[(i * 4 + wave) * 512]);
    }
    if (tid < 64) sMask[tid] = amask[bI * NSEQ + kb0 + tid];
    __syncthreads();

    f32x4 accS[4];
#pragma unroll
    for (int j = 0; j < 4; j++) accS[j] = zero;
#pragma unroll
    for (int kk = 0; kk < 2; kk++) {
      f16x8 af = *(const f16x8*)&sQ[(wave * 16 + l15) * 64 + kk * 32 + q4 * 8];
      f16x8 bf[4];
#pragma unroll
      for (int nj = 0; nj < 4; nj++)
        bf[nj] = *(const f16x8*)&sK[(nj * 16 + l15) * 64 + kk * 32 + q4 * 8];
#pragma unroll
      for (int nj = 0; nj < 4; nj++)
        accS[nj] = __builtin_amdgcn_mfma_f32_16x16x32_f16(af, bf[nj], accS[nj], 0, 0, 0);
    }
    bool mok[4];
    int gk[4];
#pragma unroll
    for (int nj = 0; nj < 4; nj++) {
      gk[nj] = nj * 16 + l15;
      mok[nj] = sMask[gk[nj]] > 0;
    }
#pragma unroll
    for (int r = 0; r < 4; r++) {
      int lq = wave * 16 + q4 * 4 + r;  // local q row 0..63; global gq = qbase+lq
      float rm = -3.0e38f;
#pragma unroll
      for (int nj = 0; nj < 4; nj++) {
        float s = accS[nj][r] * 0.125f;
        bool ok = mok[nj] && (!diag || gk[nj] <= lq);
        s = ok ? s : -1.0e9f;
        accS[nj][r] = s;
        rm = fmaxf(rm, s);
      }
#pragma unroll
      for (int o = 1; o < 16; o <<= 1) rm = fmaxf(rm, __shfl_xor(rm, o));
      float mold = mrow[r];
      float mnew = fmaxf(mold, rm);
      float alpha = __expf(mold - mnew);
      float rsum = 0.f;
#pragma unroll
      for (int nj = 0; nj < 4; nj++) {
        float p = __expf(accS[nj][r] - mnew);
        rsum += p;
        sPw[(q4 * 4 + r) * 64 + nj * 16 + l15] = (f16)p;
      }
#pragma unroll
      for (int o = 1; o < 16; o <<= 1) rsum += __shfl_xor(rsum, o);
      lrow[r] = lrow[r] * alpha + rsum;
      mrow[r] = mnew;
#pragma unroll
      for (int dj = 0; dj < 4; dj++) accO[dj][r] *= alpha;
    }
    // PV (sP is per-wave private; compiler's lgkmcnt covers write->read)
#pragma unroll
    for (int kk = 0; kk < 2; kk++) {
      f16x8 pf = *(const f16x8*)&sPw[l15 * 64 + kk * 32 + q4 * 8];
      f16x8 vf[4];
#pragma unroll
      for (int dj = 0; dj < 4; dj++)
        vf[dj] = *(const f16x8*)&sVT[(dj * 16 + l15) * 64 + kk * 32 + q4 * 8];
#pragma unroll
      for (int dj = 0; dj < 4; dj++)
        accO[dj] = __builtin_amdgcn_mfma_f32_16x16x32_f16(pf, vf[dj], accO[dj], 0, 0, 0);
    }
  }
  // epilogue: divide by l, scatter to o_concat[token][h*64+d]
#pragma unroll
  for (int r = 0; r < 4; r++) {
    float inv = 1.f / lrow[r];
    int s = qbase + wave * 16 + q4 * 4 + r;
    size_t rowoff = ((size_t)bI * NSEQ + s) * DMODEL + h * HDIM;
#pragma unroll
    for (int dj = 0; dj < 4; dj++)
      oc[rowoff + dj * 16 + l15] = (f16)(accO[dj][r] * inv);
  }
}

// ---------------- router: wave-per-token, NO global atomics ----------------
__global__ __launch_bounds__(256) void router_kernel(
    const float* __restrict__ xmid, const float* __restrict__ normw,
    const float* __restrict__ rw, int2* __restrict__ metaE,
    float2* __restrict__ metaS, float* __restrict__ blockpsum) {
  int wave = threadIdx.x >> 6, lane = threadIdx.x & 63;
  int t = blockIdx.x * 4 + wave;
  __shared__ float sprob[4][8];

  const float4* xr = (const float4*)(xmid + (size_t)t * DMODEL);
  const float4* wr = (const float4*)normw;
  float4 v[4];
  float ss = 0.f;
#pragma unroll
  for (int i = 0; i < 4; i++) {
    v[i] = xr[lane * 4 + i];
    ss += v[i].x * v[i].x + v[i].y * v[i].y + v[i].z * v[i].z + v[i].w * v[i].w;
  }
#pragma unroll
  for (int o = 32; o > 0; o >>= 1) ss += __shfl_xor(ss, o);
  float rstd = rsqrtf(ss / (float)DMODEL + 1e-6f);

  float part[8] = {0, 0, 0, 0, 0, 0, 0, 0};
#pragma unroll
  for (int i = 0; i < 4; i++) {
    float4 wv = wr[lane * 4 + i];
    float hv[4] = {v[i].x * rstd * wv.x, v[i].y * rstd * wv.y,
                   v[i].z * rstd * wv.z, v[i].w * rstd * wv.w};
#pragma unroll
    for (int j = 0; j < 4; j++) {
      int row = lane * 16 + i * 4 + j;
      const float4* rr = (const float4*)(rw + (size_t)row * NEXP);
      float4 a = rr[0], b = rr[1];
      part[0] += hv[j] * a.x; part[1] += hv[j] * a.y;
      part[2] += hv[j] * a.z; part[3] += hv[j] * a.w;
      part[4] += hv[j] * b.x; part[5] += hv[j] * b.y;
      part[6] += hv[j] * b.z; part[7] += hv[j] * b.w;
    }
  }
#pragma unroll
  for (int o = 1; o < 64; o <<= 1)
#pragma unroll
    for (int e = 0; e < 8; e++) part[e] += __shfl_xor(part[e], o);

  if (lane == 0) {
    float mx = -3.0e38f;
#pragma unroll
    for (int e = 0; e < 8; e++) mx = fmaxf(mx, part[e]);
    float probs[8], sum = 0.f;
#pragma unroll
    for (int e = 0; e < 8; e++) { probs[e] = __expf(part[e] - mx); sum += probs[e]; }
    float inv = 1.f / sum;
#pragma unroll
    for (int e = 0; e < 8; e++) { probs[e] *= inv; sprob[wave][e] = probs[e]; }
    int e0 = 0;
#pragma unroll
    for (int e = 1; e < 8; e++) if (part[e] > part[e0]) e0 = e;
    int e1 = (e0 == 0) ? 1 : 0;
#pragma unroll
    for (int e = 0; e < 8; e++) if (e != e0 && part[e] > part[e1]) e1 = e;
    metaE[t] = make_int2(e0, e1);
    metaS[t] = make_float2(probs[e0], probs[e1]);
  }
  __syncthreads();
  if (threadIdx.x < 8)
    blockpsum[blockIdx.x * 8 + threadIdx.x] =
        sprob[0][threadIdx.x] + sprob[1][threadIdx.x] +
        sprob[2][threadIdx.x] + sprob[3][threadIdx.x];
}

// ---------------- scatter: one block per expert, deterministic prefix sum ----
__global__ __launch_bounds__(256) void scatter_kernel(
    const int2* __restrict__ metaE, int* __restrict__ list,
    int* __restrict__ metaP, int* __restrict__ cnt) {
  int e = blockIdx.x;
  int tid = threadIdx.x, lane = tid & 63, w = tid >> 6;
  __shared__ int wsum[4];
  __shared__ int sbase;
  if (tid == 0) sbase = 0;
  __syncthreads();
  for (int c = 0; c < NTOK; c += 256) {
    int tok = c + tid;
    int2 me = metaE[tok];
    bool m0 = (me.x == e), m1 = (me.y == e);
    bool m = m0 || m1;
    unsigned long long mask = __ballot(m);
    int wpre = __popcll(mask & ((1ull << lane) - 1ull));
    if (lane == 0) wsum[w] = __popcll(mask);
    __syncthreads();
    int base0 = sbase;
    int pre = wpre;
    for (int i = 0; i < w; i++) pre += wsum[i];
    int tot = wsum[0] + wsum[1] + wsum[2] + wsum[3];
    if (m) {
      int pos = base0 + pre;
      list[e * NTOK + base0 + pre] = tok;
      metaP[tok * 2 + (m0 ? 0 : 1)] = pos;
    }
    __syncthreads();
    if (tid == 0) sbase = base0 + tot;
  }
  __syncthreads();
  if (tid == 0) cnt[e] = sbase;
}

// ---------------- finalize: base offsets + balancing loss + counts ----------
__global__ __launch_bounds__(256) void finalize_kernel(
    const int* __restrict__ cnt, const float* __restrict__ blockpsum,
    int* __restrict__ base, float* __restrict__ out_tail) {
  int tid = threadIdx.x;
  int e = tid & 7, slot = tid >> 3;  // 32 slots per expert
  float acc = 0.f;
  for (int i = slot; i < 1024; i += 32) acc += blockpsum[i * 8 + e];
  __shared__ float red[256];
  red[tid] = acc;
  __syncthreads();
  for (int s = 128; s >= 8; s >>= 1) {
    if (tid < s) red[tid] += red[tid + s];
    __syncthreads();
  }
  if (tid == 0) {
    int b = 0;
#pragma unroll
    for (int i = 0; i < 8; i++) { base[i] = b; b += cnt[i]; }
    base[8] = b;
    float loss = 0.f;
#pragma unroll
    for (int i = 0; i < 8; i++)
      loss += ((float)cnt[i] / (float)NPAIR) * (red[i] / (float)NTOK);
    out_tail[0] = loss * (float)NEXP;
#pragma unroll
    for (int i = 0; i < 8; i++) out_tail[1 + i] = (float)cnt[i];
  }
}

// ---------------- final combine (sums split-K halves) ----------------
__global__ void combine_kernel(const float* __restrict__ xmid, const float* __restrict__ yv,
                               const float* __restrict__ yv2,
                               const int2* __restrict__ metaE, const int* __restrict__ metaP,
                               const float2* __restrict__ metaS,
                               const int* __restrict__ base, float* __restrict__ out) {
  int t = blockIdx.x, tid = threadIdx.x;
  int2 me = metaE[t];
  float2 sc = metaS[t];
  size_t s0 = (size_t)(base[me.x] + metaP[t * 2 + 0]) * DMODEL;
  size_t s1 = (size_t)(base[me.y] + metaP[t * 2 + 1]) * DMODEL;
  float4 a = ((const float4*)(xmid + (size_t)t * DMODEL))[tid];
  float4 y0a = ((const float4*)(yv + s0))[tid];
  float4 y0b = ((const float4*)(yv2 + s0))[tid];
  float4 y1a = ((const float4*)(yv + s1))[tid];
  float4 y1b = ((const float4*)(yv2 + s1))[tid];
  float4 o;
  o.x = a.x + sc.x * (y0a.x + y0b.x) + sc.y * (y1a.x + y1b.x);
  o.y = a.y + sc.x * (y0a.y + y0b.y) + sc.y * (y1a.y + y1b.y);
  o.z = a.z + sc.x * (y0a.z + y0b.z) + sc.y * (y1a.z + y1b.z);
  o.w = a.w + sc.x * (y0a.w + y0b.w) + sc.y * (y1a.w + y1b.w);
  ((float4*)(out + (size_t)t * DMODEL))[tid] = o;
}

// ---------------------------------------------------------------------------
extern "C" void kernel_launch(void* const* d_in, const int* in_sizes, int n_in,
                              void* d_out, int out_size, void* d_ws, size_t ws_size,
                              hipStream_t stream) {
  (void)in_sizes; (void)n_in; (void)out_size; (void)ws_size;
  const float* x    = (const float*)d_in[0];
  const int*   am   = (const int*)d_in[1];
  const float* anw  = (const float*)d_in[2];
  const float* wq   = (const float*)d_in[3];
  const float* wk   = (const float*)d_in[4];
  const float* wv   = (const float*)d_in[5];
  const float* wo   = (const float*)d_in[6];
  const float* mnw  = (const float*)d_in[7];
  const float* rw   = (const float*)d_in[8];
  const float* w1   = (const float*)d_in[9];
  const float* b1   = (const float*)d_in[10];
  const float* w2   = (const float*)d_in[11];
  const float* b2   = (const float*)d_in[12];
  float* out = (float*)d_out;
  char* ws = (char*)d_ws;

  f16* wqkvT = (f16*)(ws + OFF_WQKVT);
  f16* woT   = (f16*)(ws + OFF_WOT);
  f16* w1T   = (f16*)(ws + OFF_W1T);
  f16* w2T   = (f16*)(ws + OFF_W2T);
  f16* hattn = (f16*)(ws + OFF_HATTN);
  f16* qb    = (f16*)(ws + OFF_Q);
  f16* kb    = (f16*)(ws + OFF_K);
  f16* vtb   = (f16*)(ws + OFF_VT);
  f16* oc    = (f16*)(ws + OFF_OC);
  float* xmid = (float*)(ws + OFF_XMID);
  f16* hmlp  = (f16*)(ws + OFF_HMLP);
  f16* hid   = (f16*)(ws + OFF_HID);
  float* y   = (float*)(ws + OFF_Y);
  float* y2  = (float*)(ws + OFF_Y2);
  int* list  = (int*)(ws + OFF_LIST);
  int2* metaE = (int2*)(ws + OFF_METAE);
  int* metaP  = (int*)(ws + OFF_METAP);
  float2* metaS = (float2*)(ws + OFF_METAS);
  float* bpsum = (float*)(ws + OFF_BPSUM);
  int* cnt   = (int*)(ws + OFF_CNT);
  int* base  = (int*)(ws + OFF_BASE);

  dim3 tb(32, 8, 1);
  transpose_cast_kernel<<<dim3(32, 32, 1), tb, 0, stream>>>(wq, wqkvT, 1024, 1024);
  transpose_cast_kernel<<<dim3(32, 32, 1), tb, 0, stream>>>(wk, wqkvT + 1024 * 1024, 1024, 1024);
  transpose_cast_kernel<<<dim3(32, 32, 1), tb, 0, stream>>>(wv, wqkvT + 2 * 1024 * 1024, 1024, 1024);
  transpose_cast_kernel<<<dim3(32, 32, 1), tb, 0, stream>>>(wo, woT, 1024, 1024);
  transpose_cast_kernel<<<dim3(128, 32, 8), tb, 0, stream>>>(w1, w1T, 1024, 4096);
  transpose_cast_kernel<<<dim3(32, 128, 8), tb, 0, stream>>>(w2, w2T, 4096, 1024);

  rmsnorm_kernel<<<NTOK, 256, 0, stream>>>(x, anw, hattn);
  gemm_qkv_kernel<<<dim3(24, 32), 256, 0, stream>>>(hattn, wqkvT, qb, kb, vtb);
  attn_kernel<<<dim3(32, 32), 256, 0, stream>>>(qb, kb, vtb, am, oc);
  gemm_o_kernel<<<dim3(8, 32), 256, 0, stream>>>(oc, woT, x, xmid);
  rmsnorm_kernel<<<NTOK, 256, 0, stream>>>(xmid, mnw, hmlp);
  router_kernel<<<1024, 256, 0, stream>>>(xmid, mnw, rw, metaE, metaS, bpsum);
  scatter_kernel<<<8, 256, 0, stream>>>(metaE, list, metaP, cnt);
  finalize_kernel<<<1, 256, 0, stream>>>(cnt, bpsum, base, out + (size_t)NTOK * DMODEL);
  gemm_moe1_kernel<<<dim3(32, 32, 8), 256, 0, stream>>>(hmlp, w1T, b1, cnt, base, list, hid);
  gemm_moe2_kernel<<<dim3(8, 32, 16), 256, 0, stream>>>(hid, w2T, b2, cnt, base, y, y2);
  combine_kernel<<<NTOK, 256, 0, stream>>>(xmid, y, y2, metaE, metaP, metaS, base, out);
}